// Round 7
// baseline (157.060 us; speedup 1.0000x reference)
//
#include <hip/hip_runtime.h>
#include <math.h>

// Problem constants
#define NB   216        // kept bins
#define W1   432        // transform width = conv1 width
#define W2   405        // conv2 output width
#define NSAMP 4096
#define NFFTC 1747

typedef __bf16 bf16x8 __attribute__((ext_vector_type(8)));
typedef float  f32x4  __attribute__((ext_vector_type(4)));
typedef unsigned int u32x4 __attribute__((ext_vector_type(4)));

__device__ __forceinline__ unsigned int bfbits(float f) {
    return (unsigned int)__builtin_bit_cast(unsigned short, (__bf16)f);
}
__device__ __forceinline__ float bf2f(unsigned int u) {
    return (float)__builtin_bit_cast(__bf16, (unsigned short)(u & 0xffff));
}

// --------------------------------------- basis table, 32-col-strip bf16 layout
// octet g: lane=g&63, ks=(g>>6)&1, nt=(g>>7)&1, kt=(g>>8)&7, st=g>>11 (0..13)
// col = st*32 + nt*16 + (lane&15) ; t = kt*64 + ks*32 + (lane>>4)*8 + e
__global__ __launch_bounds__(256) void k_basis32(unsigned short* __restrict__ basf) {
    int g = blockIdx.x * 256 + threadIdx.x;      // 28,672 octets
    int lane = g & 63;
    int ks = (g >> 6) & 1;
    int nt = (g >> 7) & 1;
    int kt = (g >> 8) & 7;
    int st = g >> 11;
    int w  = st * 32 + nt * 16 + (lane & 15);
    int t0 = kt * 64 + ks * 32 + (lane >> 4) * 8;
    unsigned int p[4] = {0u, 0u, 0u, 0u};
    if (w < W1) {
        int k = (w < NB) ? (24 + w) : (w - 192);
        #pragma unroll
        for (int e = 0; e < 8; ++e) {
            int m = (k * (t0 + e)) % NFFTC;
            float ang = (float)m * (float)(6.283185307179586 / 1747.0);
            float c = (w < NB) ? cosf(ang) : -sinf(ang);
            unsigned int bits = bfbits(c * (1.f / 512.f));
            p[e >> 1] |= bits << ((e & 1) * 16);
        }
    }
    u32x4 v = {p[0], p[1], p[2], p[3]};
    *(u32x4*)(basf + (size_t)g * 8) = v;
}

// ------------------- FUSED: X->bf16 -> DFT(MFMA, B direct from L2) -> conv1
// block = 32 rows (4 samples) x 448 cols ; 1024 blocks ; ZERO barriers in GEMM
__global__ __launch_bounds__(256, 2) void k_fused(const float* __restrict__ x,
        const unsigned short* __restrict__ basf,
        const float* __restrict__ w1k, const float* __restrict__ a1w1,
        const float* __restrict__ a1b1, const float* __restrict__ a1w2,
        const float* __restrict__ a1b2,
        unsigned short* __restrict__ C1, float* __restrict__ part1) {
    __shared__ __attribute__((aligned(16))) unsigned short Al[16384]; // 32 KB; later Ys[32][456]
    __shared__ float ps[4][2];
    int tid = threadIdx.x, blk = blockIdx.x;
    int wv = tid >> 6, lane = tid & 63;
    int rh = wv & 1, nh = wv >> 1;          // row-half, col-half-of-strip
    int kg = lane >> 4, col16 = lane & 15;

    // ---- stage A: X fp32 -> bf16 packed fragments (read once, coalesced 32B)
    {
        int ksA = (tid >> 6) & 1, rhA = tid >> 7;
        const float* xrow = x + (size_t)(blk * 32 + rhA * 16 + (lane & 15)) * 512
                              + ksA * 32 + (lane >> 4) * 8;
        #pragma unroll
        for (int i = 0; i < 8; ++i) {
            f32x4 a = *(const f32x4*)(xrow + i * 64);
            f32x4 b = *(const f32x4*)(xrow + i * 64 + 4);
            u32x4 v;
            v[0] = bfbits(a[0]) | (bfbits(a[1]) << 16);
            v[1] = bfbits(a[2]) | (bfbits(a[3]) << 16);
            v[2] = bfbits(b[0]) | (bfbits(b[1]) << 16);
            v[3] = bfbits(b[2]) | (bfbits(b[3]) << 16);
            *(u32x4*)&Al[(size_t)(tid + 256 * i) * 8] = v;
        }
    }
    __syncthreads();

    // ---- hoist A fragments to registers, pinned (prevent LDS remat)
    bf16x8 fa[8][2];
    #pragma unroll
    for (int kt = 0; kt < 8; ++kt) {
        #pragma unroll
        for (int ks = 0; ks < 2; ++ks)
            fa[kt][ks] = *(const bf16x8*)&Al[(((kt * 2 + rh) * 2 + ks) * 64 + lane) * 8];
        asm volatile("" : "+v"(fa[kt][0]), "+v"(fa[kt][1]));
    }

    // ---- main GEMM: 14 strips x 16 ksteps; fb straight from global (L2-hot);
    //      1 load : 1 MFMA, no barriers, compiler-pipelined vmcnt
    f32x4 acc[14];
    #pragma unroll
    for (int i = 0; i < 14; ++i) acc[i] = (f32x4){0.f, 0.f, 0.f, 0.f};
    const char* bb = (const char*)basf + nh * 2048 + (size_t)lane * 16;
    #pragma unroll
    for (int st = 0; st < 14; ++st) {
        #pragma unroll
        for (int kt = 0; kt < 8; ++kt) {
            bf16x8 f0 = *(const bf16x8*)(bb + st * 32768 + kt * 4096);
            bf16x8 f1 = *(const bf16x8*)(bb + st * 32768 + kt * 4096 + 1024);
            acc[st] = __builtin_amdgcn_mfma_f32_16x16x32_bf16(fa[kt][0], f0, acc[st], 0, 0, 0);
            acc[st] = __builtin_amdgcn_mfma_f32_16x16x32_bf16(fa[kt][1], f1, acc[st], 0, 0, 0);
        }
    }

    // ---- per-sample Y sums, free from acc (padding cols are exact zeros)
    {
        float s = 0.f;
        #pragma unroll
        for (int st = 0; st < 14; ++st) {
            #pragma unroll
            for (int e = 0; e < 4; ++e) s += acc[st][e];
        }
        #pragma unroll
        for (int m = 1; m < 32; m <<= 1) s += __shfl_xor(s, m);
        if (lane == 0)  ps[wv][0] = s;       // sample rh*2   (this wave's cols)
        if (lane == 32) ps[wv][1] = s;       // sample rh*2+1
    }

    // ---- write Y (bf16) into reused Al region: Ys[32 rows][456]
    unsigned short* Ys = Al;
    #pragma unroll
    for (int st = 0; st < 14; ++st) {
        int col = st * 32 + nh * 16 + col16;
        #pragma unroll
        for (int e = 0; e < 4; ++e) {
            int row = rh * 16 + kg * 4 + e;
            Ys[row * 456 + col] = (unsigned short)bfbits(acc[st][e]);
        }
    }
    __syncthreads();

    // ---- fused conv1: wave wv handles sample s = wv
    int s = wv;
    float p1 = (ps[(s >> 1)][s & 1] + ps[(s >> 1) + 2][s & 1]) * (1.f / (8.f * W1));
    float h = fmaxf(p1 * a1w1[0] + a1b1[0], 0.f);
    float l[4], mx = -1e30f;
    #pragma unroll
    for (int k = 0; k < 4; ++k) { l[k] = (h * a1w2[k] + a1b2[k]) * (1.f / 30.f); mx = fmaxf(mx, l[k]); }
    float es = 0.f;
    #pragma unroll
    for (int k = 0; k < 4; ++k) { l[k] = expf(l[k] - mx); es += l[k]; }
    float inv = 1.f / es;
    float at[4] = {l[0] * inv, l[1] * inv, l[2] * inv, l[3] * inv};

    int o = lane & 15, wl = lane >> 4;
    float kr[8];
    #pragma unroll
    for (int hh = 0; hh < 8; ++hh) {
        float kv = 0.f;
        #pragma unroll
        for (int k = 0; k < 4; ++k) kv = fmaf(at[k], w1k[k * 128 + o * 8 + hh], kv);
        kr[hh] = kv;
    }
    int b = blk * 4 + s;
    unsigned short* c1o = C1 + (size_t)b * (432 * 16);
    float ssum = 0.f, ssq = 0.f;
    for (int j = 0; j < 54; ++j) {
        int w0 = (wl + 4 * j) * 2;            // even w; pair (w0, w0+1)
        float a0 = 0.f, a1 = 0.f;
        #pragma unroll
        for (int hh = 0; hh < 8; ++hh) {
            unsigned int y2 = *(const unsigned int*)&Ys[(s * 8 + hh) * 456 + w0];
            a0 = fmaf(kr[hh], bf2f(y2), a0);
            a1 = fmaf(kr[hh], bf2f(y2 >> 16), a1);
        }
        c1o[w0 * 16 + o]       = (unsigned short)bfbits(a0);
        c1o[(w0 + 1) * 16 + o] = (unsigned short)bfbits(a1);
        ssum += a0 + a1; ssq = fmaf(a0, a0, fmaf(a1, a1, ssq));
    }
    ssum += __shfl_xor(ssum, 16); ssq += __shfl_xor(ssq, 16);
    ssum += __shfl_xor(ssum, 32); ssq += __shfl_xor(ssq, 32);
    if (lane < 16) {
        part1[lane * NSAMP + b] = ssum;
        part1[(16 + lane) * NSAMP + b] = ssq;
    }
}

// ---------------- stats reduce + finalize: block i handles channel i
__global__ __launch_bounds__(256) void k_statfin2(const float* __restrict__ part,
        const float* __restrict__ g, const float* __restrict__ bb,
        float* __restrict__ ss, float cnt) {
    __shared__ float red[2][4];
    int i = blockIdx.x, tid = threadIdx.x;
    const f32x4* psr = (const f32x4*)(part + (size_t)i * NSAMP);
    const f32x4* qs = (const f32x4*)(part + (size_t)(16 + i) * NSAMP);
    float s = 0.f, q = 0.f;
    #pragma unroll
    for (int jj = 0; jj < 4; ++jj) {
        int j = tid + jj * 256;
        f32x4 a = psr[j], c = qs[j];
        s += a[0] + a[1] + a[2] + a[3];
        q += c[0] + c[1] + c[2] + c[3];
    }
    #pragma unroll
    for (int m = 32; m; m >>= 1) { s += __shfl_xor(s, m); q += __shfl_xor(q, m); }
    if ((tid & 63) == 0) { red[0][tid >> 6] = s; red[1][tid >> 6] = q; }
    __syncthreads();
    if (tid == 0) {
        float sum = red[0][0] + red[0][1] + red[0][2] + red[0][3];
        float sq  = red[1][0] + red[1][1] + red[1][2] + red[1][3];
        float mean = sum / cnt;
        float var  = sq / cnt - mean * mean;
        float sc = g[i] * rsqrtf(var + 1e-5f);
        ss[i] = sc;
        ss[16 + i] = bb[i] - mean * sc;
    }
}

// ----------------------------------------------------- w2k im2col transpose
__global__ void k_w2kT(const float* __restrict__ w2k, float* __restrict__ w2kT) {
    int idx = blockIdx.x * 256 + threadIdx.x;
    if (idx < 10240) {
        int k = idx / 2560, rem = idx - k * 2560;
        int oc = rem / 160, r2 = rem - oc * 160;
        int tp = r2 >> 4, ic = r2 & 15;
        w2kT[idx] = w2k[((k * 16 + oc) * 16 + ic) * 10 + tp];
    }
}

// -------------------------------- conv2 via MFMA (BN1+relu fused, att2, stats)
#define H1T_STR 24     // shorts per row
#define H1T_ROWS 448
__global__ __launch_bounds__(256) void k_conv2(const unsigned short* __restrict__ C1b,
        const float* __restrict__ w2kT, const float* __restrict__ a2w1,
        const float* __restrict__ a2b1, const float* __restrict__ a2w2,
        const float* __restrict__ a2b2, const float* __restrict__ ss,
        unsigned short* __restrict__ H2Tb, float* __restrict__ part2) {
    __shared__ __attribute__((aligned(16))) unsigned short H1T[H1T_ROWS * H1T_STR];
    __shared__ __attribute__((aligned(16))) unsigned short Bl[16 * 160];
    __shared__ float p2p[4][16];
    __shared__ float sred[4][2][16];
    int b = blockIdx.x, tid = threadIdx.x;
    int wv = tid >> 6, lane = tid & 63;

    // ---- stage C1 [w][16ic] -> BN1+relu -> bf16 -> H1T rows (vectorized)
    for (int w = tid; w < W1; w += 256) {
        const u32x4* src = (const u32x4*)(C1b + ((size_t)b * W1 + w) * 16);
        u32x4 v0 = src[0], v1 = src[1];
        unsigned int op[8];
        #pragma unroll
        for (int i = 0; i < 8; ++i) {
            unsigned int u = (i < 4) ? v0[i] : v1[i - 4];
            float a = fmaxf(fmaf(bf2f(u),       ss[2*i],     ss[16 + 2*i]),     0.f);
            float c = fmaxf(fmaf(bf2f(u >> 16), ss[2*i + 1], ss[16 + 2*i + 1]), 0.f);
            op[i] = bfbits(a) | (bfbits(c) << 16);
        }
        *(u32x4*)&H1T[w * H1T_STR]     = (u32x4){op[0], op[1], op[2], op[3]};
        *(u32x4*)&H1T[w * H1T_STR + 8] = (u32x4){op[4], op[5], op[6], op[7]};
    }
    if (tid < 128) {   // zero pad rows 432..447
        int r = 432 + (tid >> 3), c = (tid & 7) * 2;
        *(unsigned int*)&H1T[r * H1T_STR + c] = 0u;
    }
    __syncthreads();

    // ---- per-channel means (conflict-free seg sums)
    {
        int chn = tid & 15, seg = tid >> 4;    // 16 segs x 27 w
        float s = 0.f;
        for (int j = 0; j < 27; ++j)
            s += bf2f((unsigned int)H1T[(seg * 27 + j) * H1T_STR + chn]);
        s += __shfl_xor(s, 16);
        s += __shfl_xor(s, 32);
        if ((lane & 48) == 0) p2p[wv][chn] = s;
    }
    __syncthreads();

    // ---- att2 (redundant per-thread, cheap)
    float hv[4];
    #pragma unroll
    for (int j = 0; j < 4; ++j) {
        float a = a2b1[j];
        #pragma unroll
        for (int i = 0; i < 16; ++i) {
            float p2 = (p2p[0][i] + p2p[1][i] + p2p[2][i] + p2p[3][i]) * (1.f / (float)W1);
            a = fmaf(a2w1[j * 16 + i], p2, a);
        }
        hv[j] = fmaxf(a, 0.f);
    }
    float l[4], mx = -1e30f;
    #pragma unroll
    for (int k = 0; k < 4; ++k) {
        float a = a2b2[k];
        #pragma unroll
        for (int j = 0; j < 4; ++j) a = fmaf(a2w2[k * 4 + j], hv[j], a);
        l[k] = a * (1.f / 30.f); mx = fmaxf(mx, l[k]);
    }
    float es = 0.f;
    #pragma unroll
    for (int k = 0; k < 4; ++k) { l[k] = expf(l[k] - mx); es += l[k]; }
    float inv = 1.f / es;
    float at0 = l[0] * inv, at1 = l[1] * inv, at2 = l[2] * inv, at3 = l[3] * inv;
    // ---- mixed kernel from pre-transposed w2kT (coalesced)
    #pragma unroll
    for (int i = 0; i < 10; ++i) {
        int idx = tid + i * 256;
        float v = at0 * w2kT[idx] + at1 * w2kT[2560 + idx]
                + at2 * w2kT[5120 + idx] + at3 * w2kT[7680 + idx];
        Bl[idx] = (unsigned short)bfbits(v);
    }
    __syncthreads();

    // ---- MFMA: 26 m-tiles of 16 w's, K=160 in 5 steps of 32
    int col = lane & 15, kg = lane >> 4;
    bf16x8 bfrag[5];
    #pragma unroll
    for (int s = 0; s < 5; ++s)
        bfrag[s] = *(const bf16x8*)&Bl[col * 160 + s * 32 + kg * 8];
    float s2 = 0.f, q2 = 0.f;
    for (int mt = wv; mt < 26; mt += 4) {
        int wbase = mt * 16;
        f32x4 acc = {0.f, 0.f, 0.f, 0.f};
        #pragma unroll
        for (int s = 0; s < 5; ++s) {
            int tp = 2 * s + (kg >> 1);
            int row = wbase + col + 3 * tp;
            bf16x8 a = *(const bf16x8*)&H1T[row * H1T_STR + (kg & 1) * 8];
            acc = __builtin_amdgcn_mfma_f32_16x16x32_bf16(a, bfrag[s], acc, 0, 0, 0);
        }
        unsigned short* hb = H2Tb + (size_t)b * (16 * W2) + (wbase + kg * 4) * 16 + col;
        #pragma unroll
        for (int r = 0; r < 4; ++r) {
            int w = wbase + kg * 4 + r;
            if (w < W2) {
                float v = acc[r];
                hb[r * 16] = (unsigned short)bfbits(v);
                s2 += v; q2 = fmaf(v, v, q2);
            }
        }
    }
    s2 += __shfl_xor(s2, 16); q2 += __shfl_xor(q2, 16);
    s2 += __shfl_xor(s2, 32); q2 += __shfl_xor(q2, 32);
    if (lane < 16) { sred[wv][0][lane] = s2; sred[wv][1][lane] = q2; }
    __syncthreads();
    if (tid < 16) {
        part2[tid * NSAMP + b] = sred[0][0][tid] + sred[1][0][tid] + sred[2][0][tid] + sred[3][0][tid];
    } else if (tid < 32) {
        int i = tid - 16;
        part2[(16 + i) * NSAMP + b] = sred[0][1][i] + sred[1][1][i] + sred[2][1][i] + sred[3][1][i];
    }
}

// --------------------------------------------- fcw -> packed bf16 pairs (once)
__global__ void k_fcT(const float* __restrict__ fcw, unsigned int* __restrict__ fcwp) {
    int p = blockIdx.x * 256 + threadIdx.x;
    if (p < 3240) {
        int idx0 = 2 * p;
        int w = idx0 >> 4, oc = idx0 & 15;
        unsigned int r[4];
        #pragma unroll
        for (int h = 0; h < 2; ++h) {
            int c = oc + h;
            float n0 = fcw[0 * 6480 + c * W2 + w];
            float n1 = fcw[1 * 6480 + c * W2 + w];
            float n2 = fcw[2 * 6480 + c * W2 + w];
            float n3 = fcw[3 * 6480 + c * W2 + w];
            r[2 * h]     = bfbits(n0) | (bfbits(n1) << 16);
            r[2 * h + 1] = bfbits(n2) | (bfbits(n3) << 16);
        }
        ((u32x4*)fcwp)[p] = (u32x4){r[0], r[1], r[2], r[3]};
    }
}

// ------------------------------------------------------------ BN2+relu+FC out
__global__ __launch_bounds__(256) void k_fc(const unsigned short* __restrict__ H2Tb,
        const float* __restrict__ ss2, const unsigned int* __restrict__ fcwp,
        const float* __restrict__ fcb, float* __restrict__ out) {
    __shared__ float red[4][4];
    int b = blockIdx.x, tid = threadIdx.x;
    const unsigned int* hb = (const unsigned int*)(H2Tb + (size_t)b * (16 * W2));
    const u32x4* fw = (const u32x4*)fcwp;
    float acc[4] = {};
    for (int p = tid; p < 3240; p += 256) {
        unsigned int u = hb[p];
        int oc = (2 * p) & 15;
        float v0 = fmaxf(fmaf(bf2f(u),       ss2[oc],     ss2[16 + oc]),     0.f);
        float v1 = fmaxf(fmaf(bf2f(u >> 16), ss2[oc + 1], ss2[16 + oc + 1]), 0.f);
        u32x4 wv4 = fw[p];
        acc[0] = fmaf(v0, bf2f(wv4[0]),       fmaf(v1, bf2f(wv4[2]),       acc[0]));
        acc[1] = fmaf(v0, bf2f(wv4[0] >> 16), fmaf(v1, bf2f(wv4[2] >> 16), acc[1]));
        acc[2] = fmaf(v0, bf2f(wv4[1]),       fmaf(v1, bf2f(wv4[3]),       acc[2]));
        acc[3] = fmaf(v0, bf2f(wv4[1] >> 16), fmaf(v1, bf2f(wv4[3] >> 16), acc[3]));
    }
    #pragma unroll
    for (int m = 1; m < 64; m <<= 1)
        #pragma unroll
        for (int n = 0; n < 4; ++n) acc[n] += __shfl_xor(acc[n], m);
    int wid = tid >> 6, lane = tid & 63;
    if (lane == 0) {
        #pragma unroll
        for (int n = 0; n < 4; ++n) red[wid][n] = acc[n];
    }
    __syncthreads();
    if (tid < 4)
        out[b * 4 + tid] = red[0][tid] + red[1][tid] + red[2][tid] + red[3][tid] + fcb[tid];
}

extern "C" void kernel_launch(void* const* d_in, const int* in_sizes, int n_in,
                              void* d_out, int out_size, void* d_ws, size_t ws_size,
                              hipStream_t stream) {
    const float* x    = (const float*)d_in[0];
    const float* w1k  = (const float*)d_in[1];
    const float* a1w1 = (const float*)d_in[2];
    const float* a1b1 = (const float*)d_in[3];
    const float* a1w2 = (const float*)d_in[4];
    const float* a1b2 = (const float*)d_in[5];
    const float* g1   = (const float*)d_in[6];
    const float* b1   = (const float*)d_in[7];
    const float* w2k  = (const float*)d_in[8];
    const float* a2w1 = (const float*)d_in[9];
    const float* a2b1 = (const float*)d_in[10];
    const float* a2w2 = (const float*)d_in[11];
    const float* a2b2 = (const float*)d_in[12];
    const float* g2   = (const float*)d_in[13];
    const float* b2   = (const float*)d_in[14];
    const float* fcw  = (const float*)d_in[15];
    const float* fcb  = (const float*)d_in[16];

    float* ws = (float*)d_ws;
    // Region Q: H2Tb bf16 ; part1/part2 @ +14,155,776 ; w2kT/fcwp after
    // Region P @ +26,542,080: C1b bf16 [b][w][16oc]
    unsigned short* H2Tb = (unsigned short*)ws;
    float*          part1 = ws + 14155776;
    float*          part2 = part1 + 32 * NSAMP;
    float*          w2kT  = part2 + 32 * NSAMP;            // 10240 floats
    unsigned int*   fcwp  = (unsigned int*)(w2kT + 10240); // 12960 u32
    unsigned short* C1b  = (unsigned short*)(ws + 26542080);
    unsigned short* basf = (unsigned short*)(ws + 26542080 + 14155776);
    float* ssf   = ws + 26542080 + 14155776 + 114688;

    k_fcT<<<13, 256, 0, stream>>>(fcw, fcwp);
    k_w2kT<<<40, 256, 0, stream>>>(w2k, w2kT);
    k_basis32<<<112, 256, 0, stream>>>(basf);
    k_fused<<<1024, 256, 0, stream>>>(x, basf, w1k, a1w1, a1b1, a1w2, a1b2, C1b, part1);
    k_statfin2<<<16, 256, 0, stream>>>(part1, g1, b1, ssf, 4096.f * 432.f);
    k_conv2<<<NSAMP, 256, 0, stream>>>(C1b, w2kT, a2w1, a2b1, a2w2, a2b2, ssf, H2Tb, part2);
    k_statfin2<<<16, 256, 0, stream>>>(part2, g2, b2, ssf + 32, 4096.f * 405.f);
    k_fc<<<NSAMP, 256, 0, stream>>>(H2Tb, ssf + 32, fcwp, fcb, (float*)d_out);
}

// Round 8
// 145.989 us; speedup vs baseline: 1.0758x; 1.0758x over previous
//
#include <hip/hip_runtime.h>
#include <math.h>

// Problem constants
#define NB   216        // kept bins
#define W1   432        // transform width = conv1 width
#define W2   405        // conv2 output width
#define NSAMP 4096
#define NFFTC 1747

typedef __bf16 bf16x8 __attribute__((ext_vector_type(8)));
typedef float  f32x4  __attribute__((ext_vector_type(4)));
typedef unsigned int u32x4 __attribute__((ext_vector_type(4)));

__device__ __forceinline__ unsigned int bfbits(float f) {
    return (unsigned int)__builtin_bit_cast(unsigned short, (__bf16)f);
}
__device__ __forceinline__ float bf2f(unsigned int u) {
    return (float)__builtin_bit_cast(__bf16, (unsigned short)(u & 0xffff));
}

// --------------------------------------- basis table, 32-col-strip bf16 layout
// octet g: lane=g&63, ks=(g>>6)&1, nt=(g>>7)&1, kt=(g>>8)&7, st=g>>11 (0..13)
// col = st*32 + nt*16 + (lane&15) ; t = kt*64 + ks*32 + (lane>>4)*8 + e
__global__ __launch_bounds__(256) void k_basis32(unsigned short* __restrict__ basf) {
    int g = blockIdx.x * 256 + threadIdx.x;      // 28,672 octets
    int lane = g & 63;
    int ks = (g >> 6) & 1;
    int nt = (g >> 7) & 1;
    int kt = (g >> 8) & 7;
    int st = g >> 11;
    int w  = st * 32 + nt * 16 + (lane & 15);
    int t0 = kt * 64 + ks * 32 + (lane >> 4) * 8;
    unsigned int p[4] = {0u, 0u, 0u, 0u};
    if (w < W1) {
        int k = (w < NB) ? (24 + w) : (w - 192);
        #pragma unroll
        for (int e = 0; e < 8; ++e) {
            int m = (k * (t0 + e)) % NFFTC;
            float ang = (float)m * (float)(6.283185307179586 / 1747.0);
            float c = (w < NB) ? cosf(ang) : -sinf(ang);
            unsigned int bits = bfbits(c * (1.f / 512.f));
            p[e >> 1] |= bits << ((e & 1) * 16);
        }
    }
    u32x4 v = {p[0], p[1], p[2], p[3]};
    *(u32x4*)(basf + (size_t)g * 8) = v;
}

// ------------------- FUSED: X->bf16 -> DFT(MFMA, B direct from L2) -> conv1
// block = 32 rows (4 samples) x 448 cols ; 1024 blocks ; zero barriers in GEMM
// kt-outer loop: fa streamed from LDS per kt (8 VGPR), acc[14] resident (56)
__global__ __launch_bounds__(256) void k_fused(const float* __restrict__ x,
        const unsigned short* __restrict__ basf,
        const float* __restrict__ w1k, const float* __restrict__ a1w1,
        const float* __restrict__ a1b1, const float* __restrict__ a1w2,
        const float* __restrict__ a1b2,
        unsigned short* __restrict__ C1, float* __restrict__ part1) {
    __shared__ __attribute__((aligned(16))) unsigned short Al[16384]; // 32 KB; later Ys[32][456]
    __shared__ float ps[4][2];
    int tid = threadIdx.x, blk = blockIdx.x;
    int wv = tid >> 6, lane = tid & 63;
    int rh = wv & 1, nh = wv >> 1;          // row-half, col-half-of-strip
    int kg = lane >> 4, col16 = lane & 15;

    // ---- stage A: X fp32 -> bf16 packed fragments (read once, coalesced 32B)
    {
        int ksA = (tid >> 6) & 1, rhA = tid >> 7;
        const float* xrow = x + (size_t)(blk * 32 + rhA * 16 + (lane & 15)) * 512
                              + ksA * 32 + (lane >> 4) * 8;
        #pragma unroll
        for (int i = 0; i < 8; ++i) {
            f32x4 a = *(const f32x4*)(xrow + i * 64);
            f32x4 b = *(const f32x4*)(xrow + i * 64 + 4);
            u32x4 v;
            v[0] = bfbits(a[0]) | (bfbits(a[1]) << 16);
            v[1] = bfbits(a[2]) | (bfbits(a[3]) << 16);
            v[2] = bfbits(b[0]) | (bfbits(b[1]) << 16);
            v[3] = bfbits(b[2]) | (bfbits(b[3]) << 16);
            *(u32x4*)&Al[(size_t)(tid + 256 * i) * 8] = v;
        }
    }
    __syncthreads();

    // ---- main GEMM: kt outer (fa from LDS, 2 reads / 28 MFMAs), fb from L2
    f32x4 acc[14];
    #pragma unroll
    for (int i = 0; i < 14; ++i) acc[i] = (f32x4){0.f, 0.f, 0.f, 0.f};
    const char* bb = (const char*)basf + nh * 2048 + (size_t)lane * 16;
    #pragma unroll
    for (int kt = 0; kt < 8; ++kt) {
        bf16x8 fa0 = *(const bf16x8*)&Al[(((kt * 2 + rh) * 2 + 0) * 64 + lane) * 8];
        bf16x8 fa1 = *(const bf16x8*)&Al[(((kt * 2 + rh) * 2 + 1) * 64 + lane) * 8];
        #pragma unroll
        for (int st = 0; st < 14; ++st) {
            bf16x8 f0 = *(const bf16x8*)(bb + st * 32768 + kt * 4096);
            bf16x8 f1 = *(const bf16x8*)(bb + st * 32768 + kt * 4096 + 1024);
            acc[st] = __builtin_amdgcn_mfma_f32_16x16x32_bf16(fa0, f0, acc[st], 0, 0, 0);
            acc[st] = __builtin_amdgcn_mfma_f32_16x16x32_bf16(fa1, f1, acc[st], 0, 0, 0);
        }
    }

    // ---- per-sample Y sums, free from acc (padding cols are exact zeros)
    {
        float s = 0.f;
        #pragma unroll
        for (int st = 0; st < 14; ++st) {
            #pragma unroll
            for (int e = 0; e < 4; ++e) s += acc[st][e];
        }
        #pragma unroll
        for (int m = 1; m < 32; m <<= 1) s += __shfl_xor(s, m);
        if (lane == 0)  ps[wv][0] = s;       // sample rh*2   (this wave's cols)
        if (lane == 32) ps[wv][1] = s;       // sample rh*2+1
    }
    __syncthreads();   // everyone done reading Al as A-fragments

    // ---- write Y (bf16) into reused Al region: Ys[32 rows][456]
    unsigned short* Ys = Al;
    #pragma unroll
    for (int st = 0; st < 14; ++st) {
        int col = st * 32 + nh * 16 + col16;
        #pragma unroll
        for (int e = 0; e < 4; ++e) {
            int row = rh * 16 + kg * 4 + e;
            Ys[row * 456 + col] = (unsigned short)bfbits(acc[st][e]);
        }
    }
    __syncthreads();

    // ---- fused conv1: wave wv handles sample s = wv
    int s = wv;
    float p1 = (ps[(s >> 1)][s & 1] + ps[(s >> 1) + 2][s & 1]) * (1.f / (8.f * W1));
    float h = fmaxf(p1 * a1w1[0] + a1b1[0], 0.f);
    float l[4], mx = -1e30f;
    #pragma unroll
    for (int k = 0; k < 4; ++k) { l[k] = (h * a1w2[k] + a1b2[k]) * (1.f / 30.f); mx = fmaxf(mx, l[k]); }
    float es = 0.f;
    #pragma unroll
    for (int k = 0; k < 4; ++k) { l[k] = expf(l[k] - mx); es += l[k]; }
    float inv = 1.f / es;
    float at[4] = {l[0] * inv, l[1] * inv, l[2] * inv, l[3] * inv};

    int o = lane & 15, wl = lane >> 4;
    float kr[8];
    #pragma unroll
    for (int hh = 0; hh < 8; ++hh) {
        float kv = 0.f;
        #pragma unroll
        for (int k = 0; k < 4; ++k) kv = fmaf(at[k], w1k[k * 128 + o * 8 + hh], kv);
        kr[hh] = kv;
    }
    int b = blk * 4 + s;
    unsigned short* c1o = C1 + (size_t)b * (432 * 16);
    float ssum = 0.f, ssq = 0.f;
    for (int j = 0; j < 54; ++j) {
        int w0 = (wl + 4 * j) * 2;            // even w; pair (w0, w0+1)
        float a0 = 0.f, a1 = 0.f;
        #pragma unroll
        for (int hh = 0; hh < 8; ++hh) {
            unsigned int y2 = *(const unsigned int*)&Ys[(s * 8 + hh) * 456 + w0];
            a0 = fmaf(kr[hh], bf2f(y2), a0);
            a1 = fmaf(kr[hh], bf2f(y2 >> 16), a1);
        }
        c1o[w0 * 16 + o]       = (unsigned short)bfbits(a0);
        c1o[(w0 + 1) * 16 + o] = (unsigned short)bfbits(a1);
        ssum += a0 + a1; ssq = fmaf(a0, a0, fmaf(a1, a1, ssq));
    }
    ssum += __shfl_xor(ssum, 16); ssq += __shfl_xor(ssq, 16);
    ssum += __shfl_xor(ssum, 32); ssq += __shfl_xor(ssq, 32);
    if (lane < 16) {
        part1[lane * NSAMP + b] = ssum;
        part1[(16 + lane) * NSAMP + b] = ssq;
    }
}

// ---------------- stats reduce + finalize: block i handles channel i
__global__ __launch_bounds__(256) void k_statfin2(const float* __restrict__ part,
        const float* __restrict__ g, const float* __restrict__ bb,
        float* __restrict__ ss, float cnt) {
    __shared__ float red[2][4];
    int i = blockIdx.x, tid = threadIdx.x;
    const f32x4* psr = (const f32x4*)(part + (size_t)i * NSAMP);
    const f32x4* qs = (const f32x4*)(part + (size_t)(16 + i) * NSAMP);
    float s = 0.f, q = 0.f;
    #pragma unroll
    for (int jj = 0; jj < 4; ++jj) {
        int j = tid + jj * 256;
        f32x4 a = psr[j], c = qs[j];
        s += a[0] + a[1] + a[2] + a[3];
        q += c[0] + c[1] + c[2] + c[3];
    }
    #pragma unroll
    for (int m = 32; m; m >>= 1) { s += __shfl_xor(s, m); q += __shfl_xor(q, m); }
    if ((tid & 63) == 0) { red[0][tid >> 6] = s; red[1][tid >> 6] = q; }
    __syncthreads();
    if (tid == 0) {
        float sum = red[0][0] + red[0][1] + red[0][2] + red[0][3];
        float sq  = red[1][0] + red[1][1] + red[1][2] + red[1][3];
        float mean = sum / cnt;
        float var  = sq / cnt - mean * mean;
        float sc = g[i] * rsqrtf(var + 1e-5f);
        ss[i] = sc;
        ss[16 + i] = bb[i] - mean * sc;
    }
}

// ----------------------------------------------------- w2k im2col transpose
__global__ void k_w2kT(const float* __restrict__ w2k, float* __restrict__ w2kT) {
    int idx = blockIdx.x * 256 + threadIdx.x;
    if (idx < 10240) {
        int k = idx / 2560, rem = idx - k * 2560;
        int oc = rem / 160, r2 = rem - oc * 160;
        int tp = r2 >> 4, ic = r2 & 15;
        w2kT[idx] = w2k[((k * 16 + oc) * 16 + ic) * 10 + tp];
    }
}

// -------------------------------- conv2 via MFMA (BN1+relu fused, att2, stats)
#define H1T_STR 24     // shorts per row
#define H1T_ROWS 448
__global__ __launch_bounds__(256) void k_conv2(const unsigned short* __restrict__ C1b,
        const float* __restrict__ w2kT, const float* __restrict__ a2w1,
        const float* __restrict__ a2b1, const float* __restrict__ a2w2,
        const float* __restrict__ a2b2, const float* __restrict__ ss,
        unsigned short* __restrict__ H2Tb, float* __restrict__ part2) {
    __shared__ __attribute__((aligned(16))) unsigned short H1T[H1T_ROWS * H1T_STR];
    __shared__ __attribute__((aligned(16))) unsigned short Bl[16 * 160];
    __shared__ float p2p[4][16];
    __shared__ float sred[4][2][16];
    int b = blockIdx.x, tid = threadIdx.x;
    int wv = tid >> 6, lane = tid & 63;

    // ---- stage C1 [w][16ic] -> BN1+relu -> bf16 -> H1T rows (vectorized)
    for (int w = tid; w < W1; w += 256) {
        const u32x4* src = (const u32x4*)(C1b + ((size_t)b * W1 + w) * 16);
        u32x4 v0 = src[0], v1 = src[1];
        unsigned int op[8];
        #pragma unroll
        for (int i = 0; i < 8; ++i) {
            unsigned int u = (i < 4) ? v0[i] : v1[i - 4];
            float a = fmaxf(fmaf(bf2f(u),       ss[2*i],     ss[16 + 2*i]),     0.f);
            float c = fmaxf(fmaf(bf2f(u >> 16), ss[2*i + 1], ss[16 + 2*i + 1]), 0.f);
            op[i] = bfbits(a) | (bfbits(c) << 16);
        }
        *(u32x4*)&H1T[w * H1T_STR]     = (u32x4){op[0], op[1], op[2], op[3]};
        *(u32x4*)&H1T[w * H1T_STR + 8] = (u32x4){op[4], op[5], op[6], op[7]};
    }
    if (tid < 128) {   // zero pad rows 432..447
        int r = 432 + (tid >> 3), c = (tid & 7) * 2;
        *(unsigned int*)&H1T[r * H1T_STR + c] = 0u;
    }
    __syncthreads();

    // ---- per-channel means (conflict-free seg sums)
    {
        int chn = tid & 15, seg = tid >> 4;    // 16 segs x 27 w
        float s = 0.f;
        for (int j = 0; j < 27; ++j)
            s += bf2f((unsigned int)H1T[(seg * 27 + j) * H1T_STR + chn]);
        s += __shfl_xor(s, 16);
        s += __shfl_xor(s, 32);
        if ((lane & 48) == 0) p2p[wv][chn] = s;
    }
    __syncthreads();

    // ---- att2 (redundant per-thread, cheap)
    float hv[4];
    #pragma unroll
    for (int j = 0; j < 4; ++j) {
        float a = a2b1[j];
        #pragma unroll
        for (int i = 0; i < 16; ++i) {
            float p2 = (p2p[0][i] + p2p[1][i] + p2p[2][i] + p2p[3][i]) * (1.f / (float)W1);
            a = fmaf(a2w1[j * 16 + i], p2, a);
        }
        hv[j] = fmaxf(a, 0.f);
    }
    float l[4], mx = -1e30f;
    #pragma unroll
    for (int k = 0; k < 4; ++k) {
        float a = a2b2[k];
        #pragma unroll
        for (int j = 0; j < 4; ++j) a = fmaf(a2w2[k * 4 + j], hv[j], a);
        l[k] = a * (1.f / 30.f); mx = fmaxf(mx, l[k]);
    }
    float es = 0.f;
    #pragma unroll
    for (int k = 0; k < 4; ++k) { l[k] = expf(l[k] - mx); es += l[k]; }
    float inv = 1.f / es;
    float at0 = l[0] * inv, at1 = l[1] * inv, at2 = l[2] * inv, at3 = l[3] * inv;
    // ---- mixed kernel from pre-transposed w2kT (coalesced)
    #pragma unroll
    for (int i = 0; i < 10; ++i) {
        int idx = tid + i * 256;
        float v = at0 * w2kT[idx] + at1 * w2kT[2560 + idx]
                + at2 * w2kT[5120 + idx] + at3 * w2kT[7680 + idx];
        Bl[idx] = (unsigned short)bfbits(v);
    }
    __syncthreads();

    // ---- MFMA: 26 m-tiles of 16 w's, K=160 in 5 steps of 32
    int col = lane & 15, kg = lane >> 4;
    bf16x8 bfrag[5];
    #pragma unroll
    for (int s = 0; s < 5; ++s)
        bfrag[s] = *(const bf16x8*)&Bl[col * 160 + s * 32 + kg * 8];
    float s2 = 0.f, q2 = 0.f;
    for (int mt = wv; mt < 26; mt += 4) {
        int wbase = mt * 16;
        f32x4 acc = {0.f, 0.f, 0.f, 0.f};
        #pragma unroll
        for (int s = 0; s < 5; ++s) {
            int tp = 2 * s + (kg >> 1);
            int row = wbase + col + 3 * tp;
            bf16x8 a = *(const bf16x8*)&H1T[row * H1T_STR + (kg & 1) * 8];
            acc = __builtin_amdgcn_mfma_f32_16x16x32_bf16(a, bfrag[s], acc, 0, 0, 0);
        }
        unsigned short* hb = H2Tb + (size_t)b * (16 * W2) + (wbase + kg * 4) * 16 + col;
        #pragma unroll
        for (int r = 0; r < 4; ++r) {
            int w = wbase + kg * 4 + r;
            if (w < W2) {
                float v = acc[r];
                hb[r * 16] = (unsigned short)bfbits(v);
                s2 += v; q2 = fmaf(v, v, q2);
            }
        }
    }
    s2 += __shfl_xor(s2, 16); q2 += __shfl_xor(q2, 16);
    s2 += __shfl_xor(s2, 32); q2 += __shfl_xor(q2, 32);
    if (lane < 16) { sred[wv][0][lane] = s2; sred[wv][1][lane] = q2; }
    __syncthreads();
    if (tid < 16) {
        part2[tid * NSAMP + b] = sred[0][0][tid] + sred[1][0][tid] + sred[2][0][tid] + sred[3][0][tid];
    } else if (tid < 32) {
        int i = tid - 16;
        part2[(16 + i) * NSAMP + b] = sred[0][1][i] + sred[1][1][i] + sred[2][1][i] + sred[3][1][i];
    }
}

// --------------------------------------------- fcw -> packed bf16 pairs (once)
__global__ void k_fcT(const float* __restrict__ fcw, unsigned int* __restrict__ fcwp) {
    int p = blockIdx.x * 256 + threadIdx.x;
    if (p < 3240) {
        int idx0 = 2 * p;
        int w = idx0 >> 4, oc = idx0 & 15;
        unsigned int r[4];
        #pragma unroll
        for (int h = 0; h < 2; ++h) {
            int c = oc + h;
            float n0 = fcw[0 * 6480 + c * W2 + w];
            float n1 = fcw[1 * 6480 + c * W2 + w];
            float n2 = fcw[2 * 6480 + c * W2 + w];
            float n3 = fcw[3 * 6480 + c * W2 + w];
            r[2 * h]     = bfbits(n0) | (bfbits(n1) << 16);
            r[2 * h + 1] = bfbits(n2) | (bfbits(n3) << 16);
        }
        ((u32x4*)fcwp)[p] = (u32x4){r[0], r[1], r[2], r[3]};
    }
}

// ------------------------------------------------------------ BN2+relu+FC out
__global__ __launch_bounds__(256) void k_fc(const unsigned short* __restrict__ H2Tb,
        const float* __restrict__ ss2, const unsigned int* __restrict__ fcwp,
        const float* __restrict__ fcb, float* __restrict__ out) {
    __shared__ float red[4][4];
    int b = blockIdx.x, tid = threadIdx.x;
    const unsigned int* hb = (const unsigned int*)(H2Tb + (size_t)b * (16 * W2));
    const u32x4* fw = (const u32x4*)fcwp;
    float acc[4] = {};
    for (int p = tid; p < 3240; p += 256) {
        unsigned int u = hb[p];
        int oc = (2 * p) & 15;
        float v0 = fmaxf(fmaf(bf2f(u),       ss2[oc],     ss2[16 + oc]),     0.f);
        float v1 = fmaxf(fmaf(bf2f(u >> 16), ss2[oc + 1], ss2[16 + oc + 1]), 0.f);
        u32x4 wv4 = fw[p];
        acc[0] = fmaf(v0, bf2f(wv4[0]),       fmaf(v1, bf2f(wv4[2]),       acc[0]));
        acc[1] = fmaf(v0, bf2f(wv4[0] >> 16), fmaf(v1, bf2f(wv4[2] >> 16), acc[1]));
        acc[2] = fmaf(v0, bf2f(wv4[1]),       fmaf(v1, bf2f(wv4[3]),       acc[2]));
        acc[3] = fmaf(v0, bf2f(wv4[1] >> 16), fmaf(v1, bf2f(wv4[3] >> 16), acc[3]));
    }
    #pragma unroll
    for (int m = 1; m < 64; m <<= 1)
        #pragma unroll
        for (int n = 0; n < 4; ++n) acc[n] += __shfl_xor(acc[n], m);
    int wid = tid >> 6, lane = tid & 63;
    if (lane == 0) {
        #pragma unroll
        for (int n = 0; n < 4; ++n) red[wid][n] = acc[n];
    }
    __syncthreads();
    if (tid < 4)
        out[b * 4 + tid] = red[0][tid] + red[1][tid] + red[2][tid] + red[3][tid] + fcb[tid];
}

extern "C" void kernel_launch(void* const* d_in, const int* in_sizes, int n_in,
                              void* d_out, int out_size, void* d_ws, size_t ws_size,
                              hipStream_t stream) {
    const float* x    = (const float*)d_in[0];
    const float* w1k  = (const float*)d_in[1];
    const float* a1w1 = (const float*)d_in[2];
    const float* a1b1 = (const float*)d_in[3];
    const float* a1w2 = (const float*)d_in[4];
    const float* a1b2 = (const float*)d_in[5];
    const float* g1   = (const float*)d_in[6];
    const float* b1   = (const float*)d_in[7];
    const float* w2k  = (const float*)d_in[8];
    const float* a2w1 = (const float*)d_in[9];
    const float* a2b1 = (const float*)d_in[10];
    const float* a2w2 = (const float*)d_in[11];
    const float* a2b2 = (const float*)d_in[12];
    const float* g2   = (const float*)d_in[13];
    const float* b2   = (const float*)d_in[14];
    const float* fcw  = (const float*)d_in[15];
    const float* fcb  = (const float*)d_in[16];

    float* ws = (float*)d_ws;
    // Region Q: H2Tb bf16 ; part1/part2 @ +14,155,776 ; w2kT/fcwp after
    // Region P @ +26,542,080: C1b bf16 [b][w][16oc]
    unsigned short* H2Tb = (unsigned short*)ws;
    float*          part1 = ws + 14155776;
    float*          part2 = part1 + 32 * NSAMP;
    float*          w2kT  = part2 + 32 * NSAMP;            // 10240 floats
    unsigned int*   fcwp  = (unsigned int*)(w2kT + 10240); // 12960 u32
    unsigned short* C1b  = (unsigned short*)(ws + 26542080);
    unsigned short* basf = (unsigned short*)(ws + 26542080 + 14155776);
    float* ssf   = ws + 26542080 + 14155776 + 114688;

    k_fcT<<<13, 256, 0, stream>>>(fcw, fcwp);
    k_w2kT<<<40, 256, 0, stream>>>(w2k, w2kT);
    k_basis32<<<112, 256, 0, stream>>>(basf);
    k_fused<<<1024, 256, 0, stream>>>(x, basf, w1k, a1w1, a1b1, a1w2, a1b2, C1b, part1);
    k_statfin2<<<16, 256, 0, stream>>>(part1, g1, b1, ssf, 4096.f * 432.f);
    k_conv2<<<NSAMP, 256, 0, stream>>>(C1b, w2kT, a2w1, a2b1, a2w2, a2b2, ssf, H2Tb, part2);
    k_statfin2<<<16, 256, 0, stream>>>(part2, g2, b2, ssf + 32, 4096.f * 405.f);
    k_fc<<<NSAMP, 256, 0, stream>>>(H2Tb, ssf + 32, fcwp, fcb, (float*)d_out);
}

// Round 9
// 145.486 us; speedup vs baseline: 1.0796x; 1.0035x over previous
//
#include <hip/hip_runtime.h>
#include <math.h>

// Problem constants
#define NB   216        // kept bins
#define W1   432        // transform width = conv1 width
#define W2   405        // conv2 output width
#define NSAMP 4096
#define NFFTC 1747

typedef __bf16 bf16x8 __attribute__((ext_vector_type(8)));
typedef float  f32x4  __attribute__((ext_vector_type(4)));
typedef unsigned int u32x4 __attribute__((ext_vector_type(4)));

__device__ __forceinline__ unsigned int bfbits(float f) {
    return (unsigned int)__builtin_bit_cast(unsigned short, (__bf16)f);
}
__device__ __forceinline__ float bf2f(unsigned int u) {
    return (float)__builtin_bit_cast(__bf16, (unsigned short)(u & 0xffff));
}
__device__ __forceinline__ void gload_lds16(const void* g, void* l) {
    __builtin_amdgcn_global_load_lds(
        (const __attribute__((address_space(1))) unsigned int*)g,
        (__attribute__((address_space(3))) unsigned int*)l, 16, 0, 0);
}

// --------------------------------------- basis table, 32-col-strip bf16 layout
// octet g: lane=g&63, ks=(g>>6)&1, nt=(g>>7)&1, kt=(g>>8)&7, st=g>>11 (0..13)
// col = st*32 + nt*16 + (lane&15) ; t = kt*64 + ks*32 + (lane>>4)*8 + e
__global__ __launch_bounds__(256) void k_basis32(unsigned short* __restrict__ basf) {
    int g = blockIdx.x * 256 + threadIdx.x;      // 28,672 octets
    int lane = g & 63;
    int ks = (g >> 6) & 1;
    int nt = (g >> 7) & 1;
    int kt = (g >> 8) & 7;
    int st = g >> 11;
    int w  = st * 32 + nt * 16 + (lane & 15);
    int t0 = kt * 64 + ks * 32 + (lane >> 4) * 8;
    unsigned int p[4] = {0u, 0u, 0u, 0u};
    if (w < W1) {
        int k = (w < NB) ? (24 + w) : (w - 192);
        #pragma unroll
        for (int e = 0; e < 8; ++e) {
            int m = (k * (t0 + e)) % NFFTC;
            float ang = (float)m * (float)(6.283185307179586 / 1747.0);
            float c = (w < NB) ? cosf(ang) : -sinf(ang);
            unsigned int bits = bfbits(c * (1.f / 512.f));
            p[e >> 1] |= bits << ((e & 1) * 16);
        }
    }
    u32x4 v = {p[0], p[1], p[2], p[3]};
    *(u32x4*)(basf + (size_t)g * 8) = v;
}

// ------------------- FUSED: X->bf16 -> DFT(MFMA, B via async LDS DMA) -> conv1
// block = 32 rows (4 samples) x 448 cols ; 1024 blocks
// GEMM pipeline: 32 units over (kt,ks,half); stage(u+1) || compute(u); 1 barrier/unit
__global__ __launch_bounds__(256) void k_fused(const float* __restrict__ x,
        const unsigned short* __restrict__ basf,
        const float* __restrict__ w1k, const float* __restrict__ a1w1,
        const float* __restrict__ a1b1, const float* __restrict__ a1w2,
        const float* __restrict__ a1b2,
        unsigned short* __restrict__ C1, float* __restrict__ part1) {
    __shared__ __attribute__((aligned(16))) unsigned short Al[16384];   // 32 KB; later Ys[32][456]
    __shared__ __attribute__((aligned(16))) unsigned short Bb[2][7168]; // 2 x 14 KB B pipe
    __shared__ float ps[4][2];
    int tid = threadIdx.x, blk = blockIdx.x;
    int wv = tid >> 6, lane = tid & 63;
    int rh = wv & 1, nh = wv >> 1;          // row-half, col-half-of-strip
    int kg = lane >> 4, col16 = lane & 15;

    // stage unit (kt,ks,half) -> Bb[buf]: 14 chunks of 1KB, chunk c=(st-half*7)*2+nt
#define STAGE_UNIT(buf, kt_, ks_, half_) do {                                   \
    for (int c = wv; c < 14; c += 4) {                                          \
        int st_ = (half_) * 7 + (c >> 1); int nt_ = c & 1;                      \
        gload_lds16((const char*)basf + (size_t)st_ * 32768 + (kt_) * 4096      \
                        + nt_ * 2048 + (ks_) * 1024 + lane * 16,                \
                    (char*)&Bb[buf][0] + c * 1024 + lane * 16);                 \
    }                                                                            \
} while (0)

    // prologue: unit 0 DMA in flight while we convert/stage A
    STAGE_UNIT(0, 0, 0, 0);

    // ---- stage A: X fp32 -> bf16 packed fragments (read once)
    {
        const float* xrow = x + (size_t)(blk * 32 + (tid >> 7) * 16 + (lane & 15)) * 512
                              + ((tid >> 6) & 1) * 32 + (lane >> 4) * 8;
        #pragma unroll
        for (int i = 0; i < 8; ++i) {
            f32x4 a = *(const f32x4*)(xrow + i * 64);
            f32x4 b = *(const f32x4*)(xrow + i * 64 + 4);
            u32x4 v;
            v[0] = bfbits(a[0]) | (bfbits(a[1]) << 16);
            v[1] = bfbits(a[2]) | (bfbits(a[3]) << 16);
            v[2] = bfbits(b[0]) | (bfbits(b[1]) << 16);
            v[3] = bfbits(b[2]) | (bfbits(b[3]) << 16);
            *(u32x4*)&Al[(size_t)(tid + 256 * i) * 8] = v;
        }
    }
    __syncthreads();   // drains A ds_writes AND unit-0 DMA

    // ---- main GEMM: 32 units; stage(u+1) issued before compute(u)
    f32x4 acc[14];
    #pragma unroll
    for (int i = 0; i < 14; ++i) acc[i] = (f32x4){0.f, 0.f, 0.f, 0.f};
    #pragma unroll
    for (int kt = 0; kt < 8; ++kt) {
        #pragma unroll
        for (int ks = 0; ks < 2; ++ks) {
            bf16x8 fa = *(const bf16x8*)&Al[((kt * 4 + rh * 2 + ks) * 64 + lane) * 8];
            #pragma unroll
            for (int half = 0; half < 2; ++half) {
                const int u = kt * 4 + ks * 2 + half;
                const int buf = u & 1;
                if (u + 1 < 32) {
                    const int un = u + 1;
                    STAGE_UNIT(buf ^ 1, un >> 2, (un >> 1) & 1, un & 1);
                }
                #pragma unroll
                for (int j = 0; j < 7; ++j) {
                    bf16x8 fb = *(const bf16x8*)&Bb[buf][(j * 2 + nh) * 512 + lane * 8];
                    acc[half * 7 + j] = __builtin_amdgcn_mfma_f32_16x16x32_bf16(
                        fa, fb, acc[half * 7 + j], 0, 0, 0);
                }
                __syncthreads();   // next buf's DMA done; this buf free
            }
        }
    }
#undef STAGE_UNIT

    // ---- per-sample Y sums, free from acc (padding cols are exact zeros)
    {
        float s = 0.f;
        #pragma unroll
        for (int st = 0; st < 14; ++st) {
            #pragma unroll
            for (int e = 0; e < 4; ++e) s += acc[st][e];
        }
        #pragma unroll
        for (int m = 1; m < 32; m <<= 1) s += __shfl_xor(s, m);
        if (lane == 0)  ps[wv][0] = s;       // sample rh*2   (this wave's cols)
        if (lane == 32) ps[wv][1] = s;       // sample rh*2+1
    }
    __syncthreads();

    // ---- write Y (bf16) into reused Al region: Ys[32 rows][456]
    unsigned short* Ys = Al;
    #pragma unroll
    for (int st = 0; st < 14; ++st) {
        int col = st * 32 + nh * 16 + col16;
        #pragma unroll
        for (int e = 0; e < 4; ++e) {
            int row = rh * 16 + kg * 4 + e;
            Ys[row * 456 + col] = (unsigned short)bfbits(acc[st][e]);
        }
    }
    __syncthreads();

    // ---- fused conv1: wave wv handles sample s = wv
    int s = wv;
    float p1 = (ps[(s >> 1)][s & 1] + ps[(s >> 1) + 2][s & 1]) * (1.f / (8.f * W1));
    float h = fmaxf(p1 * a1w1[0] + a1b1[0], 0.f);
    float l[4], mx = -1e30f;
    #pragma unroll
    for (int k = 0; k < 4; ++k) { l[k] = (h * a1w2[k] + a1b2[k]) * (1.f / 30.f); mx = fmaxf(mx, l[k]); }
    float es = 0.f;
    #pragma unroll
    for (int k = 0; k < 4; ++k) { l[k] = expf(l[k] - mx); es += l[k]; }
    float inv = 1.f / es;
    float at[4] = {l[0] * inv, l[1] * inv, l[2] * inv, l[3] * inv};

    int o = lane & 15, wl = lane >> 4;
    float kr[8];
    #pragma unroll
    for (int hh = 0; hh < 8; ++hh) {
        float kv = 0.f;
        #pragma unroll
        for (int k = 0; k < 4; ++k) kv = fmaf(at[k], w1k[k * 128 + o * 8 + hh], kv);
        kr[hh] = kv;
    }
    int b = blk * 4 + s;
    unsigned short* c1o = C1 + (size_t)b * (432 * 16);
    float ssum = 0.f, ssq = 0.f;
    for (int j = 0; j < 54; ++j) {
        int w0 = (wl + 4 * j) * 2;            // even w; pair (w0, w0+1)
        float a0 = 0.f, a1 = 0.f;
        #pragma unroll
        for (int hh = 0; hh < 8; ++hh) {
            unsigned int y2 = *(const unsigned int*)&Ys[(s * 8 + hh) * 456 + w0];
            a0 = fmaf(kr[hh], bf2f(y2), a0);
            a1 = fmaf(kr[hh], bf2f(y2 >> 16), a1);
        }
        c1o[w0 * 16 + o]       = (unsigned short)bfbits(a0);
        c1o[(w0 + 1) * 16 + o] = (unsigned short)bfbits(a1);
        ssum += a0 + a1; ssq = fmaf(a0, a0, fmaf(a1, a1, ssq));
    }
    ssum += __shfl_xor(ssum, 16); ssq += __shfl_xor(ssq, 16);
    ssum += __shfl_xor(ssum, 32); ssq += __shfl_xor(ssq, 32);
    if (lane < 16) {
        part1[lane * NSAMP + b] = ssum;
        part1[(16 + lane) * NSAMP + b] = ssq;
    }
}

// ---------------- stats reduce + finalize: block i handles channel i
__global__ __launch_bounds__(256) void k_statfin2(const float* __restrict__ part,
        const float* __restrict__ g, const float* __restrict__ bb,
        float* __restrict__ ss, float cnt) {
    __shared__ float red[2][4];
    int i = blockIdx.x, tid = threadIdx.x;
    const f32x4* psr = (const f32x4*)(part + (size_t)i * NSAMP);
    const f32x4* qs = (const f32x4*)(part + (size_t)(16 + i) * NSAMP);
    float s = 0.f, q = 0.f;
    #pragma unroll
    for (int jj = 0; jj < 4; ++jj) {
        int j = tid + jj * 256;
        f32x4 a = psr[j], c = qs[j];
        s += a[0] + a[1] + a[2] + a[3];
        q += c[0] + c[1] + c[2] + c[3];
    }
    #pragma unroll
    for (int m = 32; m; m >>= 1) { s += __shfl_xor(s, m); q += __shfl_xor(q, m); }
    if ((tid & 63) == 0) { red[0][tid >> 6] = s; red[1][tid >> 6] = q; }
    __syncthreads();
    if (tid == 0) {
        float sum = red[0][0] + red[0][1] + red[0][2] + red[0][3];
        float sq  = red[1][0] + red[1][1] + red[1][2] + red[1][3];
        float mean = sum / cnt;
        float var  = sq / cnt - mean * mean;
        float sc = g[i] * rsqrtf(var + 1e-5f);
        ss[i] = sc;
        ss[16 + i] = bb[i] - mean * sc;
    }
}

// ----------------------------------------------------- w2k im2col transpose
__global__ void k_w2kT(const float* __restrict__ w2k, float* __restrict__ w2kT) {
    int idx = blockIdx.x * 256 + threadIdx.x;
    if (idx < 10240) {
        int k = idx / 2560, rem = idx - k * 2560;
        int oc = rem / 160, r2 = rem - oc * 160;
        int tp = r2 >> 4, ic = r2 & 15;
        w2kT[idx] = w2k[((k * 16 + oc) * 16 + ic) * 10 + tp];
    }
}

// -------------------------------- conv2 via MFMA (BN1+relu fused, att2, stats)
#define H1T_STR 24     // shorts per row
#define H1T_ROWS 448
__global__ __launch_bounds__(256) void k_conv2(const unsigned short* __restrict__ C1b,
        const float* __restrict__ w2kT, const float* __restrict__ a2w1,
        const float* __restrict__ a2b1, const float* __restrict__ a2w2,
        const float* __restrict__ a2b2, const float* __restrict__ ss,
        unsigned short* __restrict__ H2Tb, float* __restrict__ part2) {
    __shared__ __attribute__((aligned(16))) unsigned short H1T[H1T_ROWS * H1T_STR];
    __shared__ __attribute__((aligned(16))) unsigned short Bl[16 * 160];
    __shared__ float p2p[4][16];
    __shared__ float sred[4][2][16];
    int b = blockIdx.x, tid = threadIdx.x;
    int wv = tid >> 6, lane = tid & 63;

    // ---- stage C1 [w][16ic] -> BN1+relu -> bf16 -> H1T rows (vectorized)
    for (int w = tid; w < W1; w += 256) {
        const u32x4* src = (const u32x4*)(C1b + ((size_t)b * W1 + w) * 16);
        u32x4 v0 = src[0], v1 = src[1];
        unsigned int op[8];
        #pragma unroll
        for (int i = 0; i < 8; ++i) {
            unsigned int u = (i < 4) ? v0[i] : v1[i - 4];
            float a = fmaxf(fmaf(bf2f(u),       ss[2*i],     ss[16 + 2*i]),     0.f);
            float c = fmaxf(fmaf(bf2f(u >> 16), ss[2*i + 1], ss[16 + 2*i + 1]), 0.f);
            op[i] = bfbits(a) | (bfbits(c) << 16);
        }
        *(u32x4*)&H1T[w * H1T_STR]     = (u32x4){op[0], op[1], op[2], op[3]};
        *(u32x4*)&H1T[w * H1T_STR + 8] = (u32x4){op[4], op[5], op[6], op[7]};
    }
    if (tid < 128) {   // zero pad rows 432..447
        int r = 432 + (tid >> 3), c = (tid & 7) * 2;
        *(unsigned int*)&H1T[r * H1T_STR + c] = 0u;
    }
    __syncthreads();

    // ---- per-channel means (conflict-free seg sums)
    {
        int chn = tid & 15, seg = tid >> 4;    // 16 segs x 27 w
        float s = 0.f;
        for (int j = 0; j < 27; ++j)
            s += bf2f((unsigned int)H1T[(seg * 27 + j) * H1T_STR + chn]);
        s += __shfl_xor(s, 16);
        s += __shfl_xor(s, 32);
        if ((lane & 48) == 0) p2p[wv][chn] = s;
    }
    __syncthreads();

    // ---- att2 (redundant per-thread, cheap)
    float hv[4];
    #pragma unroll
    for (int j = 0; j < 4; ++j) {
        float a = a2b1[j];
        #pragma unroll
        for (int i = 0; i < 16; ++i) {
            float p2 = (p2p[0][i] + p2p[1][i] + p2p[2][i] + p2p[3][i]) * (1.f / (float)W1);
            a = fmaf(a2w1[j * 16 + i], p2, a);
        }
        hv[j] = fmaxf(a, 0.f);
    }
    float l[4], mx = -1e30f;
    #pragma unroll
    for (int k = 0; k < 4; ++k) {
        float a = a2b2[k];
        #pragma unroll
        for (int j = 0; j < 4; ++j) a = fmaf(a2w2[k * 4 + j], hv[j], a);
        l[k] = a * (1.f / 30.f); mx = fmaxf(mx, l[k]);
    }
    float es = 0.f;
    #pragma unroll
    for (int k = 0; k < 4; ++k) { l[k] = expf(l[k] - mx); es += l[k]; }
    float inv = 1.f / es;
    float at0 = l[0] * inv, at1 = l[1] * inv, at2 = l[2] * inv, at3 = l[3] * inv;
    // ---- mixed kernel from pre-transposed w2kT (coalesced)
    #pragma unroll
    for (int i = 0; i < 10; ++i) {
        int idx = tid + i * 256;
        float v = at0 * w2kT[idx] + at1 * w2kT[2560 + idx]
                + at2 * w2kT[5120 + idx] + at3 * w2kT[7680 + idx];
        Bl[idx] = (unsigned short)bfbits(v);
    }
    __syncthreads();

    // ---- MFMA: 26 m-tiles of 16 w's, K=160 in 5 steps of 32
    int col = lane & 15, kg = lane >> 4;
    bf16x8 bfrag[5];
    #pragma unroll
    for (int s = 0; s < 5; ++s)
        bfrag[s] = *(const bf16x8*)&Bl[col * 160 + s * 32 + kg * 8];
    float s2 = 0.f, q2 = 0.f;
    for (int mt = wv; mt < 26; mt += 4) {
        int wbase = mt * 16;
        f32x4 acc = {0.f, 0.f, 0.f, 0.f};
        #pragma unroll
        for (int s = 0; s < 5; ++s) {
            int tp = 2 * s + (kg >> 1);
            int row = wbase + col + 3 * tp;
            bf16x8 a = *(const bf16x8*)&H1T[row * H1T_STR + (kg & 1) * 8];
            acc = __builtin_amdgcn_mfma_f32_16x16x32_bf16(a, bfrag[s], acc, 0, 0, 0);
        }
        unsigned short* hb = H2Tb + (size_t)b * (16 * W2) + (wbase + kg * 4) * 16 + col;
        #pragma unroll
        for (int r = 0; r < 4; ++r) {
            int w = wbase + kg * 4 + r;
            if (w < W2) {
                float v = acc[r];
                hb[r * 16] = (unsigned short)bfbits(v);
                s2 += v; q2 = fmaf(v, v, q2);
            }
        }
    }
    s2 += __shfl_xor(s2, 16); q2 += __shfl_xor(q2, 16);
    s2 += __shfl_xor(s2, 32); q2 += __shfl_xor(q2, 32);
    if (lane < 16) { sred[wv][0][lane] = s2; sred[wv][1][lane] = q2; }
    __syncthreads();
    if (tid < 16) {
        part2[tid * NSAMP + b] = sred[0][0][tid] + sred[1][0][tid] + sred[2][0][tid] + sred[3][0][tid];
    } else if (tid < 32) {
        int i = tid - 16;
        part2[(16 + i) * NSAMP + b] = sred[0][1][i] + sred[1][1][i] + sred[2][1][i] + sred[3][1][i];
    }
}

// --------------------------------------------- fcw -> packed bf16 pairs (once)
__global__ void k_fcT(const float* __restrict__ fcw, unsigned int* __restrict__ fcwp) {
    int p = blockIdx.x * 256 + threadIdx.x;
    if (p < 3240) {
        int idx0 = 2 * p;
        int w = idx0 >> 4, oc = idx0 & 15;
        unsigned int r[4];
        #pragma unroll
        for (int h = 0; h < 2; ++h) {
            int c = oc + h;
            float n0 = fcw[0 * 6480 + c * W2 + w];
            float n1 = fcw[1 * 6480 + c * W2 + w];
            float n2 = fcw[2 * 6480 + c * W2 + w];
            float n3 = fcw[3 * 6480 + c * W2 + w];
            r[2 * h]     = bfbits(n0) | (bfbits(n1) << 16);
            r[2 * h + 1] = bfbits(n2) | (bfbits(n3) << 16);
        }
        ((u32x4*)fcwp)[p] = (u32x4){r[0], r[1], r[2], r[3]};
    }
}

// ------------------------------------------------------------ BN2+relu+FC out
__global__ __launch_bounds__(256) void k_fc(const unsigned short* __restrict__ H2Tb,
        const float* __restrict__ ss2, const unsigned int* __restrict__ fcwp,
        const float* __restrict__ fcb, float* __restrict__ out) {
    __shared__ float red[4][4];
    int b = blockIdx.x, tid = threadIdx.x;
    const unsigned int* hb = (const unsigned int*)(H2Tb + (size_t)b * (16 * W2));
    const u32x4* fw = (const u32x4*)fcwp;
    float acc[4] = {};
    for (int p = tid; p < 3240; p += 256) {
        unsigned int u = hb[p];
        int oc = (2 * p) & 15;
        float v0 = fmaxf(fmaf(bf2f(u),       ss2[oc],     ss2[16 + oc]),     0.f);
        float v1 = fmaxf(fmaf(bf2f(u >> 16), ss2[oc + 1], ss2[16 + oc + 1]), 0.f);
        u32x4 wv4 = fw[p];
        acc[0] = fmaf(v0, bf2f(wv4[0]),       fmaf(v1, bf2f(wv4[2]),       acc[0]));
        acc[1] = fmaf(v0, bf2f(wv4[0] >> 16), fmaf(v1, bf2f(wv4[2] >> 16), acc[1]));
        acc[2] = fmaf(v0, bf2f(wv4[1]),       fmaf(v1, bf2f(wv4[3]),       acc[2]));
        acc[3] = fmaf(v0, bf2f(wv4[1] >> 16), fmaf(v1, bf2f(wv4[3] >> 16), acc[3]));
    }
    #pragma unroll
    for (int m = 1; m < 64; m <<= 1)
        #pragma unroll
        for (int n = 0; n < 4; ++n) acc[n] += __shfl_xor(acc[n], m);
    int wid = tid >> 6, lane = tid & 63;
    if (lane == 0) {
        #pragma unroll
        for (int n = 0; n < 4; ++n) red[wid][n] = acc[n];
    }
    __syncthreads();
    if (tid < 4)
        out[b * 4 + tid] = red[0][tid] + red[1][tid] + red[2][tid] + red[3][tid] + fcb[tid];
}

extern "C" void kernel_launch(void* const* d_in, const int* in_sizes, int n_in,
                              void* d_out, int out_size, void* d_ws, size_t ws_size,
                              hipStream_t stream) {
    const float* x    = (const float*)d_in[0];
    const float* w1k  = (const float*)d_in[1];
    const float* a1w1 = (const float*)d_in[2];
    const float* a1b1 = (const float*)d_in[3];
    const float* a1w2 = (const float*)d_in[4];
    const float* a1b2 = (const float*)d_in[5];
    const float* g1   = (const float*)d_in[6];
    const float* b1   = (const float*)d_in[7];
    const float* w2k  = (const float*)d_in[8];
    const float* a2w1 = (const float*)d_in[9];
    const float* a2b1 = (const float*)d_in[10];
    const float* a2w2 = (const float*)d_in[11];
    const float* a2b2 = (const float*)d_in[12];
    const float* g2   = (const float*)d_in[13];
    const float* b2   = (const float*)d_in[14];
    const float* fcw  = (const float*)d_in[15];
    const float* fcb  = (const float*)d_in[16];

    float* ws = (float*)d_ws;
    // Region Q: H2Tb bf16 ; part1/part2 @ +14,155,776 ; w2kT/fcwp after
    // Region P @ +26,542,080: C1b bf16 [b][w][16oc]
    unsigned short* H2Tb = (unsigned short*)ws;
    float*          part1 = ws + 14155776;
    float*          part2 = part1 + 32 * NSAMP;
    float*          w2kT  = part2 + 32 * NSAMP;            // 10240 floats
    unsigned int*   fcwp  = (unsigned int*)(w2kT + 10240); // 12960 u32
    unsigned short* C1b  = (unsigned short*)(ws + 26542080);
    unsigned short* basf = (unsigned short*)(ws + 26542080 + 14155776);
    float* ssf   = ws + 26542080 + 14155776 + 114688;

    k_fcT<<<13, 256, 0, stream>>>(fcw, fcwp);
    k_w2kT<<<40, 256, 0, stream>>>(w2k, w2kT);
    k_basis32<<<112, 256, 0, stream>>>(basf);
    k_fused<<<1024, 256, 0, stream>>>(x, basf, w1k, a1w1, a1b1, a1w2, a1b2, C1b, part1);
    k_statfin2<<<16, 256, 0, stream>>>(part1, g1, b1, ssf, 4096.f * 432.f);
    k_conv2<<<NSAMP, 256, 0, stream>>>(C1b, w2kT, a2w1, a2b1, a2w2, a2b2, ssf, H2Tb, part2);
    k_statfin2<<<16, 256, 0, stream>>>(part2, g2, b2, ssf + 32, 4096.f * 405.f);
    k_fc<<<NSAMP, 256, 0, stream>>>(H2Tb, ssf + 32, fcwp, fcb, (float*)d_out);
}

// Round 10
// 112.935 us; speedup vs baseline: 1.3907x; 1.2882x over previous
//
#include <hip/hip_runtime.h>
#include <math.h>

// Problem constants
#define NB   216        // kept bins
#define W1   432        // transform width = conv1 width
#define W2   405        // conv2 output width
#define NSAMP 4096
#define NFFTC 1747

typedef __bf16 bf16x8 __attribute__((ext_vector_type(8)));
typedef float  f32x4  __attribute__((ext_vector_type(4)));
typedef unsigned int u32x4 __attribute__((ext_vector_type(4)));
typedef unsigned int u32x2 __attribute__((ext_vector_type(2)));

__device__ __forceinline__ unsigned int bfbits(float f) {
    return (unsigned int)__builtin_bit_cast(unsigned short, (__bf16)f);
}
__device__ __forceinline__ float bf2f(unsigned int u) {
    return (float)__builtin_bit_cast(__bf16, (unsigned short)(u & 0xffff));
}

// ---------------- merged prep: basis (tile-major) + fcw pack + w2k transpose
// basf octet g: lane=g&63, kq=(g>>6)&15, nt=g>>10 (0..27)
// col = nt*16 + (lane&15) ; t = kq*32 + (lane>>4)*8 + e
__global__ __launch_bounds__(256) void k_prep(unsigned short* __restrict__ basf,
        const float* __restrict__ fcw, unsigned int* __restrict__ fcwp,
        const float* __restrict__ w2k, float* __restrict__ w2kT) {
    int blk = blockIdx.x, tid = threadIdx.x;
    if (blk < 112) {                       // ---- basis table
        int g = blk * 256 + tid;           // 28,672 octets
        int lane = g & 63;
        int kq = (g >> 6) & 15;
        int nt = g >> 10;
        int w  = nt * 16 + (lane & 15);
        int t0 = kq * 32 + (lane >> 4) * 8;
        unsigned int p[4] = {0u, 0u, 0u, 0u};
        if (w < W1) {
            int k = (w < NB) ? (24 + w) : (w - 192);
            #pragma unroll
            for (int e = 0; e < 8; ++e) {
                int m = (k * (t0 + e)) % NFFTC;
                float ang = (float)m * (float)(6.283185307179586 / 1747.0);
                float c = (w < NB) ? cosf(ang) : -sinf(ang);
                unsigned int bits = bfbits(c * (1.f / 512.f));
                p[e >> 1] |= bits << ((e & 1) * 16);
            }
        }
        u32x4 v = {p[0], p[1], p[2], p[3]};
        *(u32x4*)(basf + (size_t)g * 8) = v;
    } else if (blk < 125) {                // ---- fcw -> packed bf16 pairs
        int p = (blk - 112) * 256 + tid;
        if (p < 3240) {
            int idx0 = 2 * p;
            int w = idx0 >> 4, oc = idx0 & 15;
            unsigned int r[4];
            #pragma unroll
            for (int h = 0; h < 2; ++h) {
                int c = oc + h;
                float n0 = fcw[0 * 6480 + c * W2 + w];
                float n1 = fcw[1 * 6480 + c * W2 + w];
                float n2 = fcw[2 * 6480 + c * W2 + w];
                float n3 = fcw[3 * 6480 + c * W2 + w];
                r[2 * h]     = bfbits(n0) | (bfbits(n1) << 16);
                r[2 * h + 1] = bfbits(n2) | (bfbits(n3) << 16);
            }
            ((u32x4*)fcwp)[p] = (u32x4){r[0], r[1], r[2], r[3]};
        }
    } else {                               // ---- w2k im2col transpose
        int idx = (blk - 125) * 256 + tid;
        if (idx < 10240) {
            int k = idx / 2560, rem = idx - k * 2560;
            int oc = rem / 160, r2 = rem - oc * 160;
            int tp = r2 >> 4, ic = r2 & 15;
            w2kT[idx] = w2k[((k * 16 + oc) * 16 + ic) * 10 + tp];
        }
    }
}

// ------------- FUSED: X->bf16 -> DFT (fb from L2, 1 fb : 2 MFMA) -> conv1
// block = 32 rows (4 samples); wave = col-quarter (7 tiles x 16 cols), both row-tiles
// LDS: one 36 KB region (A-frags 32 KB, then Ys_T 448x40 shorts); 4 blocks/CU
__global__ __launch_bounds__(256, 4) void k_fused(const float* __restrict__ x,
        const unsigned short* __restrict__ basf,
        const float* __restrict__ w1k, const float* __restrict__ a1w1,
        const float* __restrict__ a1b1, const float* __restrict__ a1w2,
        const float* __restrict__ a1b2,
        unsigned short* __restrict__ C1, float* __restrict__ part1) {
    __shared__ __attribute__((aligned(16))) unsigned short Al[17920]; // 35840 B
    __shared__ float ps[4][4];
    int tid = threadIdx.x, blk = blockIdx.x;
    int wv = tid >> 6, lane = tid & 63;
    int cq = wv;                           // col-quarter
    int kg = lane >> 4, col16 = lane & 15;

    // ---- stage A: X fp32 -> bf16 packed fragments (read once)
    {
        const float* xrow = x + (size_t)(blk * 32 + (tid >> 7) * 16 + (lane & 15)) * 512
                              + ((tid >> 6) & 1) * 32 + (lane >> 4) * 8;
        #pragma unroll
        for (int i = 0; i < 8; ++i) {
            f32x4 a = *(const f32x4*)(xrow + i * 64);
            f32x4 b = *(const f32x4*)(xrow + i * 64 + 4);
            u32x4 v;
            v[0] = bfbits(a[0]) | (bfbits(a[1]) << 16);
            v[1] = bfbits(a[2]) | (bfbits(a[3]) << 16);
            v[2] = bfbits(b[0]) | (bfbits(b[1]) << 16);
            v[3] = bfbits(b[2]) | (bfbits(b[3]) << 16);
            *(u32x4*)&Al[(size_t)(tid + 256 * i) * 8] = v;
        }
    }
    __syncthreads();

    // ---- GEMM: 16 ksteps x 7 col-tiles; fb from L2, each fb feeds 2 MFMAs
    f32x4 acc[2][7];
    #pragma unroll
    for (int rh = 0; rh < 2; ++rh)
        #pragma unroll
        for (int j = 0; j < 7; ++j) acc[rh][j] = (f32x4){0.f, 0.f, 0.f, 0.f};
    #pragma unroll
    for (int kq = 0; kq < 16; ++kq) {
        bf16x8 fa0 = *(const bf16x8*)&Al[(((kq >> 1) * 4 + 0 + (kq & 1)) * 64 + lane) * 8];
        bf16x8 fa1 = *(const bf16x8*)&Al[(((kq >> 1) * 4 + 2 + (kq & 1)) * 64 + lane) * 8];
        #pragma unroll
        for (int j = 0; j < 7; ++j) {
            bf16x8 fb = *(const bf16x8*)(basf + (size_t)(((cq * 7 + j) * 16 + kq) * 64 + lane) * 8);
            acc[0][j] = __builtin_amdgcn_mfma_f32_16x16x32_bf16(fa0, fb, acc[0][j], 0, 0, 0);
            acc[1][j] = __builtin_amdgcn_mfma_f32_16x16x32_bf16(fa1, fb, acc[1][j], 0, 0, 0);
        }
    }

    // ---- per-sample Y partial sums straight from acc
    {
        float s0 = 0.f, s1 = 0.f;
        #pragma unroll
        for (int j = 0; j < 7; ++j)
            #pragma unroll
            for (int e = 0; e < 4; ++e) { s0 += acc[0][j][e]; s1 += acc[1][j][e]; }
        #pragma unroll
        for (int m = 1; m < 32; m <<= 1) { s0 += __shfl_xor(s0, m); s1 += __shfl_xor(s1, m); }
        if ((lane & 31) == 0) {
            int hi = lane >> 5;            // lanes 0-31: rows 0-7 of tile; 32-63: rows 8-15
            ps[wv][hi] = s0;               // samples 0/1
            ps[wv][2 + hi] = s1;           // samples 2/3
        }
    }
    __syncthreads();   // all fa reads done; Al free for Ys_T

    // ---- write Y transposed: Ys_T[col][row], stride 40 shorts (b64 packed)
    #pragma unroll
    for (int rh = 0; rh < 2; ++rh)
        #pragma unroll
        for (int j = 0; j < 7; ++j) {
            int col = cq * 112 + j * 16 + col16;
            u32x2 pk;
            pk[0] = bfbits(acc[rh][j][0]) | (bfbits(acc[rh][j][1]) << 16);
            pk[1] = bfbits(acc[rh][j][2]) | (bfbits(acc[rh][j][3]) << 16);
            *(u32x2*)&Al[col * 40 + rh * 16 + kg * 4] = pk;
        }
    __syncthreads();

    // ---- fused conv1: wave = sample s; quarter-wave = 4 output channels
    int s = wv;
    float p1 = (ps[0][s] + ps[1][s] + ps[2][s] + ps[3][s]) * (1.f / (8.f * W1));
    float h = fmaxf(p1 * a1w1[0] + a1b1[0], 0.f);
    float l[4], mx = -1e30f;
    #pragma unroll
    for (int k = 0; k < 4; ++k) { l[k] = (h * a1w2[k] + a1b2[k]) * (1.f / 30.f); mx = fmaxf(mx, l[k]); }
    float es = 0.f;
    #pragma unroll
    for (int k = 0; k < 4; ++k) { l[k] = expf(l[k] - mx); es += l[k]; }
    float inv = 1.f / es;
    float at[4] = {l[0] * inv, l[1] * inv, l[2] * inv, l[3] * inv};

    int q = lane >> 4, i = lane & 15;
    float kr[4][8];
    #pragma unroll
    for (int c = 0; c < 4; ++c)
        #pragma unroll
        for (int ch = 0; ch < 8; ++ch) {
            float kv = 0.f;
            #pragma unroll
            for (int k = 0; k < 4; ++k)
                kv = fmaf(at[k], w1k[k * 128 + (q * 4 + c) * 8 + ch], kv);
            kr[c][ch] = kv;
        }
    int b = blk * 4 + s;
    unsigned short* c1o = C1 + (size_t)b * (432 * 16);
    float ssum[4] = {}, ssq[4] = {};
    for (int pass = 0; pass < 27; ++pass) {
        int w = i + 16 * pass;
        bf16x8 y8 = *(const bf16x8*)&Al[w * 40 + s * 8];   // one b128: 8 channels
        float yf[8];
        #pragma unroll
        for (int ch = 0; ch < 8; ++ch) yf[ch] = (float)y8[ch];
        u32x2 pk = {0u, 0u};
        #pragma unroll
        for (int c = 0; c < 4; ++c) {
            float a = 0.f;
            #pragma unroll
            for (int ch = 0; ch < 8; ++ch) a = fmaf(kr[c][ch], yf[ch], a);
            ssum[c] += a; ssq[c] = fmaf(a, a, ssq[c]);
            pk[c >> 1] |= bfbits(a) << ((c & 1) * 16);
        }
        *(u32x2*)&c1o[w * 16 + q * 4] = pk;
    }
    #pragma unroll
    for (int m = 1; m < 16; m <<= 1)
        #pragma unroll
        for (int c = 0; c < 4; ++c) { ssum[c] += __shfl_xor(ssum[c], m); ssq[c] += __shfl_xor(ssq[c], m); }
    if (i == 0) {
        #pragma unroll
        for (int c = 0; c < 4; ++c) {
            part1[(q * 4 + c) * NSAMP + b] = ssum[c];
            part1[(16 + q * 4 + c) * NSAMP + b] = ssq[c];
        }
    }
}

// ---------------- stats reduce + finalize: block i handles channel i
__global__ __launch_bounds__(256) void k_statfin2(const float* __restrict__ part,
        const float* __restrict__ g, const float* __restrict__ bb,
        float* __restrict__ ss, float cnt) {
    __shared__ float red[2][4];
    int i = blockIdx.x, tid = threadIdx.x;
    const f32x4* psr = (const f32x4*)(part + (size_t)i * NSAMP);
    const f32x4* qs = (const f32x4*)(part + (size_t)(16 + i) * NSAMP);
    float s = 0.f, q = 0.f;
    #pragma unroll
    for (int jj = 0; jj < 4; ++jj) {
        int j = tid + jj * 256;
        f32x4 a = psr[j], c = qs[j];
        s += a[0] + a[1] + a[2] + a[3];
        q += c[0] + c[1] + c[2] + c[3];
    }
    #pragma unroll
    for (int m = 32; m; m >>= 1) { s += __shfl_xor(s, m); q += __shfl_xor(q, m); }
    if ((tid & 63) == 0) { red[0][tid >> 6] = s; red[1][tid >> 6] = q; }
    __syncthreads();
    if (tid == 0) {
        float sum = red[0][0] + red[0][1] + red[0][2] + red[0][3];
        float sq  = red[1][0] + red[1][1] + red[1][2] + red[1][3];
        float mean = sum / cnt;
        float var  = sq / cnt - mean * mean;
        float sc = g[i] * rsqrtf(var + 1e-5f);
        ss[i] = sc;
        ss[16 + i] = bb[i] - mean * sc;
    }
}

// -------------------------------- conv2 via MFMA (BN1+relu fused, att2, stats)
#define H1T_STR 24     // shorts per row
#define H1T_ROWS 448
__global__ __launch_bounds__(256) void k_conv2(const unsigned short* __restrict__ C1b,
        const float* __restrict__ w2kT, const float* __restrict__ a2w1,
        const float* __restrict__ a2b1, const float* __restrict__ a2w2,
        const float* __restrict__ a2b2, const float* __restrict__ ss,
        unsigned short* __restrict__ H2Tb, float* __restrict__ part2) {
    __shared__ __attribute__((aligned(16))) unsigned short H1T[H1T_ROWS * H1T_STR];
    __shared__ __attribute__((aligned(16))) unsigned short Bl[16 * 160];
    __shared__ float p2p[4][16];
    __shared__ float sred[4][2][16];
    int b = blockIdx.x, tid = threadIdx.x;
    int wv = tid >> 6, lane = tid & 63;

    // ---- stage C1 [w][16ic] -> BN1+relu -> bf16 -> H1T rows (vectorized)
    for (int w = tid; w < W1; w += 256) {
        const u32x4* src = (const u32x4*)(C1b + ((size_t)b * W1 + w) * 16);
        u32x4 v0 = src[0], v1 = src[1];
        unsigned int op[8];
        #pragma unroll
        for (int i = 0; i < 8; ++i) {
            unsigned int u = (i < 4) ? v0[i] : v1[i - 4];
            float a = fmaxf(fmaf(bf2f(u),       ss[2*i],     ss[16 + 2*i]),     0.f);
            float c = fmaxf(fmaf(bf2f(u >> 16), ss[2*i + 1], ss[16 + 2*i + 1]), 0.f);
            op[i] = bfbits(a) | (bfbits(c) << 16);
        }
        *(u32x4*)&H1T[w * H1T_STR]     = (u32x4){op[0], op[1], op[2], op[3]};
        *(u32x4*)&H1T[w * H1T_STR + 8] = (u32x4){op[4], op[5], op[6], op[7]};
    }
    if (tid < 128) {   // zero pad rows 432..447
        int r = 432 + (tid >> 3), c = (tid & 7) * 2;
        *(unsigned int*)&H1T[r * H1T_STR + c] = 0u;
    }
    __syncthreads();

    // ---- per-channel means (conflict-free seg sums)
    {
        int chn = tid & 15, seg = tid >> 4;    // 16 segs x 27 w
        float s = 0.f;
        for (int j = 0; j < 27; ++j)
            s += bf2f((unsigned int)H1T[(seg * 27 + j) * H1T_STR + chn]);
        s += __shfl_xor(s, 16);
        s += __shfl_xor(s, 32);
        if ((lane & 48) == 0) p2p[wv][chn] = s;
    }
    __syncthreads();

    // ---- att2 (redundant per-thread, cheap)
    float hv[4];
    #pragma unroll
    for (int j = 0; j < 4; ++j) {
        float a = a2b1[j];
        #pragma unroll
        for (int i = 0; i < 16; ++i) {
            float p2 = (p2p[0][i] + p2p[1][i] + p2p[2][i] + p2p[3][i]) * (1.f / (float)W1);
            a = fmaf(a2w1[j * 16 + i], p2, a);
        }
        hv[j] = fmaxf(a, 0.f);
    }
    float l[4], mx = -1e30f;
    #pragma unroll
    for (int k = 0; k < 4; ++k) {
        float a = a2b2[k];
        #pragma unroll
        for (int j = 0; j < 4; ++j) a = fmaf(a2w2[k * 4 + j], hv[j], a);
        l[k] = a * (1.f / 30.f); mx = fmaxf(mx, l[k]);
    }
    float es = 0.f;
    #pragma unroll
    for (int k = 0; k < 4; ++k) { l[k] = expf(l[k] - mx); es += l[k]; }
    float inv = 1.f / es;
    float at0 = l[0] * inv, at1 = l[1] * inv, at2 = l[2] * inv, at3 = l[3] * inv;
    // ---- mixed kernel from pre-transposed w2kT (coalesced)
    #pragma unroll
    for (int i = 0; i < 10; ++i) {
        int idx = tid + i * 256;
        float v = at0 * w2kT[idx] + at1 * w2kT[2560 + idx]
                + at2 * w2kT[5120 + idx] + at3 * w2kT[7680 + idx];
        Bl[idx] = (unsigned short)bfbits(v);
    }
    __syncthreads();

    // ---- MFMA: 26 m-tiles of 16 w's, K=160 in 5 steps of 32
    int col = lane & 15, kg = lane >> 4;
    bf16x8 bfrag[5];
    #pragma unroll
    for (int s = 0; s < 5; ++s)
        bfrag[s] = *(const bf16x8*)&Bl[col * 160 + s * 32 + kg * 8];
    float s2 = 0.f, q2 = 0.f;
    for (int mt = wv; mt < 26; mt += 4) {
        int wbase = mt * 16;
        f32x4 acc = {0.f, 0.f, 0.f, 0.f};
        #pragma unroll
        for (int s = 0; s < 5; ++s) {
            int tp = 2 * s + (kg >> 1);
            int row = wbase + col + 3 * tp;
            bf16x8 a = *(const bf16x8*)&H1T[row * H1T_STR + (kg & 1) * 8];
            acc = __builtin_amdgcn_mfma_f32_16x16x32_bf16(a, bfrag[s], acc, 0, 0, 0);
        }
        unsigned short* hb = H2Tb + (size_t)b * (16 * W2) + (wbase + kg * 4) * 16 + col;
        #pragma unroll
        for (int r = 0; r < 4; ++r) {
            int w = wbase + kg * 4 + r;
            if (w < W2) {
                float v = acc[r];
                hb[r * 16] = (unsigned short)bfbits(v);
                s2 += v; q2 = fmaf(v, v, q2);
            }
        }
    }
    s2 += __shfl_xor(s2, 16); q2 += __shfl_xor(q2, 16);
    s2 += __shfl_xor(s2, 32); q2 += __shfl_xor(q2, 32);
    if (lane < 16) { sred[wv][0][lane] = s2; sred[wv][1][lane] = q2; }
    __syncthreads();
    if (tid < 16) {
        part2[tid * NSAMP + b] = sred[0][0][tid] + sred[1][0][tid] + sred[2][0][tid] + sred[3][0][tid];
    } else if (tid < 32) {
        int i = tid - 16;
        part2[(16 + i) * NSAMP + b] = sred[0][1][i] + sred[1][1][i] + sred[2][1][i] + sred[3][1][i];
    }
}

// ------------------------------------------------------------ BN2+relu+FC out
__global__ __launch_bounds__(256) void k_fc(const unsigned short* __restrict__ H2Tb,
        const float* __restrict__ ss2, const unsigned int* __restrict__ fcwp,
        const float* __restrict__ fcb, float* __restrict__ out) {
    __shared__ float red[4][4];
    int b = blockIdx.x, tid = threadIdx.x;
    const unsigned int* hb = (const unsigned int*)(H2Tb + (size_t)b * (16 * W2));
    const u32x4* fw = (const u32x4*)fcwp;
    float acc[4] = {};
    for (int p = tid; p < 3240; p += 256) {
        unsigned int u = hb[p];
        int oc = (2 * p) & 15;
        float v0 = fmaxf(fmaf(bf2f(u),       ss2[oc],     ss2[16 + oc]),     0.f);
        float v1 = fmaxf(fmaf(bf2f(u >> 16), ss2[oc + 1], ss2[16 + oc + 1]), 0.f);
        u32x4 wv4 = fw[p];
        acc[0] = fmaf(v0, bf2f(wv4[0]),       fmaf(v1, bf2f(wv4[2]),       acc[0]));
        acc[1] = fmaf(v0, bf2f(wv4[0] >> 16), fmaf(v1, bf2f(wv4[2] >> 16), acc[1]));
        acc[2] = fmaf(v0, bf2f(wv4[1]),       fmaf(v1, bf2f(wv4[3]),       acc[2]));
        acc[3] = fmaf(v0, bf2f(wv4[1] >> 16), fmaf(v1, bf2f(wv4[3] >> 16), acc[3]));
    }
    #pragma unroll
    for (int m = 1; m < 64; m <<= 1)
        #pragma unroll
        for (int n = 0; n < 4; ++n) acc[n] += __shfl_xor(acc[n], m);
    int wid = tid >> 6, lane = tid & 63;
    if (lane == 0) {
        #pragma unroll
        for (int n = 0; n < 4; ++n) red[wid][n] = acc[n];
    }
    __syncthreads();
    if (tid < 4)
        out[b * 4 + tid] = red[0][tid] + red[1][tid] + red[2][tid] + red[3][tid] + fcb[tid];
}

extern "C" void kernel_launch(void* const* d_in, const int* in_sizes, int n_in,
                              void* d_out, int out_size, void* d_ws, size_t ws_size,
                              hipStream_t stream) {
    const float* x    = (const float*)d_in[0];
    const float* w1k  = (const float*)d_in[1];
    const float* a1w1 = (const float*)d_in[2];
    const float* a1b1 = (const float*)d_in[3];
    const float* a1w2 = (const float*)d_in[4];
    const float* a1b2 = (const float*)d_in[5];
    const float* g1   = (const float*)d_in[6];
    const float* b1   = (const float*)d_in[7];
    const float* w2k  = (const float*)d_in[8];
    const float* a2w1 = (const float*)d_in[9];
    const float* a2b1 = (const float*)d_in[10];
    const float* a2w2 = (const float*)d_in[11];
    const float* a2b2 = (const float*)d_in[12];
    const float* g2   = (const float*)d_in[13];
    const float* b2   = (const float*)d_in[14];
    const float* fcw  = (const float*)d_in[15];
    const float* fcb  = (const float*)d_in[16];

    float* ws = (float*)d_ws;
    // Region Q: H2Tb bf16 ; part1/part2 @ +14,155,776 ; w2kT/fcwp after
    // Region P @ +26,542,080: C1b bf16 [b][w][16oc]
    unsigned short* H2Tb = (unsigned short*)ws;
    float*          part1 = ws + 14155776;
    float*          part2 = part1 + 32 * NSAMP;
    float*          w2kT  = part2 + 32 * NSAMP;            // 10240 floats
    unsigned int*   fcwp  = (unsigned int*)(w2kT + 10240); // 12960 u32
    unsigned short* C1b  = (unsigned short*)(ws + 26542080);
    unsigned short* basf = (unsigned short*)(ws + 26542080 + 14155776);
    float* ssf   = ws + 26542080 + 14155776 + 114688;

    k_prep<<<165, 256, 0, stream>>>(basf, fcw, fcwp, w2k, w2kT);
    k_fused<<<1024, 256, 0, stream>>>(x, basf, w1k, a1w1, a1b1, a1w2, a1b2, C1b, part1);
    k_statfin2<<<16, 256, 0, stream>>>(part1, g1, b1, ssf, 4096.f * 432.f);
    k_conv2<<<NSAMP, 256, 0, stream>>>(C1b, w2kT, a2w1, a2b1, a2w2, a2b2, ssf, H2Tb, part2);
    k_statfin2<<<16, 256, 0, stream>>>(part2, g2, b2, ssf + 32, 4096.f * 405.f);
    k_fc<<<NSAMP, 256, 0, stream>>>(H2Tb, ssf + 32, fcwp, fcb, (float*)d_out);
}

// Round 11
// 105.952 us; speedup vs baseline: 1.4824x; 1.0659x over previous
//
#include <hip/hip_runtime.h>
#include <math.h>

// Problem constants
#define NB   216        // kept bins
#define W1   432        // transform width = conv1 width
#define W2   405        // conv2 output width
#define NSAMP 4096
#define NFFTC 1747

typedef __bf16 bf16x8 __attribute__((ext_vector_type(8)));
typedef float  f32x4  __attribute__((ext_vector_type(4)));
typedef unsigned int u32x4 __attribute__((ext_vector_type(4)));
typedef unsigned int u32x2 __attribute__((ext_vector_type(2)));

__device__ __forceinline__ unsigned int bfbits(float f) {
    return (unsigned int)__builtin_bit_cast(unsigned short, (__bf16)f);
}
__device__ __forceinline__ float bf2f(unsigned int u) {
    return (float)__builtin_bit_cast(__bf16, (unsigned short)(u & 0xffff));
}

// ---------------- merged prep: basis (tile-major) + fcw pack + w2k transpose
// basf octet g: lane=g&63, kq=(g>>6)&15, nt=g>>10 (0..27)
// col = nt*16 + (lane&15) ; t = kq*32 + (lane>>4)*8 + e
__global__ __launch_bounds__(256) void k_prep(unsigned short* __restrict__ basf,
        const float* __restrict__ fcw, unsigned int* __restrict__ fcwp,
        const float* __restrict__ w2k, float* __restrict__ w2kT) {
    int blk = blockIdx.x, tid = threadIdx.x;
    if (blk < 112) {                       // ---- basis table
        int g = blk * 256 + tid;           // 28,672 octets
        int lane = g & 63;
        int kq = (g >> 6) & 15;
        int nt = g >> 10;
        int w  = nt * 16 + (lane & 15);
        int t0 = kq * 32 + (lane >> 4) * 8;
        unsigned int p[4] = {0u, 0u, 0u, 0u};
        if (w < W1) {
            int k = (w < NB) ? (24 + w) : (w - 192);
            #pragma unroll
            for (int e = 0; e < 8; ++e) {
                int m = (k * (t0 + e)) % NFFTC;
                float ang = (float)m * (float)(6.283185307179586 / 1747.0);
                float c = (w < NB) ? cosf(ang) : -sinf(ang);
                unsigned int bits = bfbits(c * (1.f / 512.f));
                p[e >> 1] |= bits << ((e & 1) * 16);
            }
        }
        u32x4 v = {p[0], p[1], p[2], p[3]};
        *(u32x4*)(basf + (size_t)g * 8) = v;
    } else if (blk < 125) {                // ---- fcw -> packed bf16 pairs
        int p = (blk - 112) * 256 + tid;
        if (p < 3240) {
            int idx0 = 2 * p;
            int w = idx0 >> 4, oc = idx0 & 15;
            unsigned int r[4];
            #pragma unroll
            for (int h = 0; h < 2; ++h) {
                int c = oc + h;
                float n0 = fcw[0 * 6480 + c * W2 + w];
                float n1 = fcw[1 * 6480 + c * W2 + w];
                float n2 = fcw[2 * 6480 + c * W2 + w];
                float n3 = fcw[3 * 6480 + c * W2 + w];
                r[2 * h]     = bfbits(n0) | (bfbits(n1) << 16);
                r[2 * h + 1] = bfbits(n2) | (bfbits(n3) << 16);
            }
            ((u32x4*)fcwp)[p] = (u32x4){r[0], r[1], r[2], r[3]};
        }
    } else {                               // ---- w2k im2col transpose
        int idx = (blk - 125) * 256 + tid;
        if (idx < 10240) {
            int k = idx / 2560, rem = idx - k * 2560;
            int oc = rem / 160, r2 = rem - oc * 160;
            int tp = r2 >> 4, ic = r2 & 15;
            w2kT[idx] = w2k[((k * 16 + oc) * 16 + ic) * 10 + tp];
        }
    }
}

// ------------- FUSED: X->bf16 -> DFT (fb from L2, 1 fb : 2 MFMA) -> conv1(MFMA)
// block = 32 rows (4 samples); wave = col-quarter (7 tiles x 16 cols), both row-tiles
__global__ __launch_bounds__(256, 4) void k_fused(const float* __restrict__ x,
        const unsigned short* __restrict__ basf,
        const float* __restrict__ w1k, const float* __restrict__ a1w1,
        const float* __restrict__ a1b1, const float* __restrict__ a1w2,
        const float* __restrict__ a1b2,
        unsigned short* __restrict__ C1, float* __restrict__ part1) {
    __shared__ __attribute__((aligned(16))) unsigned short Al[17920]; // 35840 B
    __shared__ float ps[4][4];
    int tid = threadIdx.x, blk = blockIdx.x;
    int wv = tid >> 6, lane = tid & 63;
    int cq = wv;                           // col-quarter
    int kg = lane >> 4, col16 = lane & 15;

    // ---- stage A: X fp32 -> bf16 packed fragments (read once)
    {
        const float* xrow = x + (size_t)(blk * 32 + (tid >> 7) * 16 + (lane & 15)) * 512
                              + ((tid >> 6) & 1) * 32 + (lane >> 4) * 8;
        #pragma unroll
        for (int i = 0; i < 8; ++i) {
            f32x4 a = *(const f32x4*)(xrow + i * 64);
            f32x4 b = *(const f32x4*)(xrow + i * 64 + 4);
            u32x4 v;
            v[0] = bfbits(a[0]) | (bfbits(a[1]) << 16);
            v[1] = bfbits(a[2]) | (bfbits(a[3]) << 16);
            v[2] = bfbits(b[0]) | (bfbits(b[1]) << 16);
            v[3] = bfbits(b[2]) | (bfbits(b[3]) << 16);
            *(u32x4*)&Al[(size_t)(tid + 256 * i) * 8] = v;
        }
    }
    __syncthreads();

    // ---- GEMM: 16 ksteps x 7 col-tiles; fb from L2, each fb feeds 2 MFMAs
    f32x4 acc[2][7];
    #pragma unroll
    for (int rh = 0; rh < 2; ++rh)
        #pragma unroll
        for (int j = 0; j < 7; ++j) acc[rh][j] = (f32x4){0.f, 0.f, 0.f, 0.f};
    #pragma unroll
    for (int kq = 0; kq < 16; ++kq) {
        bf16x8 fa0 = *(const bf16x8*)&Al[(((kq >> 1) * 4 + 0 + (kq & 1)) * 64 + lane) * 8];
        bf16x8 fa1 = *(const bf16x8*)&Al[(((kq >> 1) * 4 + 2 + (kq & 1)) * 64 + lane) * 8];
        #pragma unroll
        for (int j = 0; j < 7; ++j) {
            bf16x8 fb = *(const bf16x8*)(basf + (size_t)(((cq * 7 + j) * 16 + kq) * 64 + lane) * 8);
            acc[0][j] = __builtin_amdgcn_mfma_f32_16x16x32_bf16(fa0, fb, acc[0][j], 0, 0, 0);
            acc[1][j] = __builtin_amdgcn_mfma_f32_16x16x32_bf16(fa1, fb, acc[1][j], 0, 0, 0);
        }
    }

    // ---- per-sample Y partial sums straight from acc
    {
        float s0 = 0.f, s1 = 0.f;
        #pragma unroll
        for (int j = 0; j < 7; ++j)
            #pragma unroll
            for (int e = 0; e < 4; ++e) { s0 += acc[0][j][e]; s1 += acc[1][j][e]; }
        #pragma unroll
        for (int m = 1; m < 32; m <<= 1) { s0 += __shfl_xor(s0, m); s1 += __shfl_xor(s1, m); }
        if ((lane & 31) == 0) {
            int hi = lane >> 5;
            ps[wv][hi] = s0;               // samples 0/1
            ps[wv][2 + hi] = s1;           // samples 2/3
        }
    }
    __syncthreads();   // all fa reads done; Al free for Ys_T

    // ---- write Y transposed: Ys_T[col][row], stride 40 shorts (b64 packed)
    #pragma unroll
    for (int rh = 0; rh < 2; ++rh)
        #pragma unroll
        for (int j = 0; j < 7; ++j) {
            int col = cq * 112 + j * 16 + col16;
            u32x2 pk;
            pk[0] = bfbits(acc[rh][j][0]) | (bfbits(acc[rh][j][1]) << 16);
            pk[1] = bfbits(acc[rh][j][2]) | (bfbits(acc[rh][j][3]) << 16);
            *(u32x2*)&Al[col * 40 + rh * 16 + kg * 4] = pk;
        }
    __syncthreads();

    // ---- fused conv1 via MFMA: wave = sample s; D[oc][16w] per tile
    int s = wv;
    float p1 = (ps[0][s] + ps[1][s] + ps[2][s] + ps[3][s]) * (1.f / (8.f * W1));
    float h = fmaxf(p1 * a1w1[0] + a1b1[0], 0.f);
    float l[4], mx = -1e30f;
    #pragma unroll
    for (int k = 0; k < 4; ++k) { l[k] = (h * a1w2[k] + a1b2[k]) * (1.f / 30.f); mx = fmaxf(mx, l[k]); }
    float es = 0.f;
    #pragma unroll
    for (int k = 0; k < 4; ++k) { l[k] = expf(l[k] - mx); es += l[k]; }
    float inv = 1.f / es;
    float at[4] = {l[0] * inv, l[1] * inv, l[2] * inv, l[3] * inv};

    // A-frag: lane holds kr[oc=col16][ch=kg*8+e]; only kg==0 slice nonzero,
    // so the garbage B values read by kg>=1 lanes are multiplied by ZERO.
    bf16x8 afrag;
    #pragma unroll
    for (int ch = 0; ch < 8; ++ch) {
        float kv = 0.f;
        #pragma unroll
        for (int k = 0; k < 4; ++k) kv = fmaf(at[k], w1k[k * 128 + col16 * 8 + ch], kv);
        afrag[ch] = (kg == 0) ? (__bf16)kv : (__bf16)0.f;
    }
    int b = blk * 4 + s;
    unsigned short* c1o = C1 + (size_t)b * (432 * 16);
    float ssum[4] = {}, ssq[4] = {};
    #pragma unroll 3
    for (int wt = 0; wt < 27; ++wt) {
        // B-frag: Y[ch 0..7][w=wt*16+col16] -- one b128, broadcast across kg
        bf16x8 bfrag = *(const bf16x8*)&Al[(wt * 16 + col16) * 40 + s * 8];
        f32x4 d = {0.f, 0.f, 0.f, 0.f};
        d = __builtin_amdgcn_mfma_f32_16x16x32_bf16(afrag, bfrag, d, 0, 0, 0);
        // D: lane holds D[oc=kg*4+i][w=wt*16+col16]
        u32x2 pk;
        pk[0] = bfbits(d[0]) | (bfbits(d[1]) << 16);
        pk[1] = bfbits(d[2]) | (bfbits(d[3]) << 16);
        *(u32x2*)&c1o[(wt * 16 + col16) * 16 + kg * 4] = pk;
        #pragma unroll
        for (int i = 0; i < 4; ++i) { ssum[i] += d[i]; ssq[i] = fmaf(d[i], d[i], ssq[i]); }
    }
    #pragma unroll
    for (int m = 1; m < 16; m <<= 1)
        #pragma unroll
        for (int c = 0; c < 4; ++c) { ssum[c] += __shfl_xor(ssum[c], m); ssq[c] += __shfl_xor(ssq[c], m); }
    if (col16 == 0) {
        #pragma unroll
        for (int c = 0; c < 4; ++c) {
            part1[(kg * 4 + c) * NSAMP + b] = ssum[c];
            part1[(16 + kg * 4 + c) * NSAMP + b] = ssq[c];
        }
    }
}

// ---------------- stats reduce + finalize: block i handles channel i
__global__ __launch_bounds__(256) void k_statfin2(const float* __restrict__ part,
        const float* __restrict__ g, const float* __restrict__ bb,
        float* __restrict__ ss, float cnt) {
    __shared__ float red[2][4];
    int i = blockIdx.x, tid = threadIdx.x;
    const f32x4* psr = (const f32x4*)(part + (size_t)i * NSAMP);
    const f32x4* qs = (const f32x4*)(part + (size_t)(16 + i) * NSAMP);
    float s = 0.f, q = 0.f;
    #pragma unroll
    for (int jj = 0; jj < 4; ++jj) {
        int j = tid + jj * 256;
        f32x4 a = psr[j], c = qs[j];
        s += a[0] + a[1] + a[2] + a[3];
        q += c[0] + c[1] + c[2] + c[3];
    }
    #pragma unroll
    for (int m = 32; m; m >>= 1) { s += __shfl_xor(s, m); q += __shfl_xor(q, m); }
    if ((tid & 63) == 0) { red[0][tid >> 6] = s; red[1][tid >> 6] = q; }
    __syncthreads();
    if (tid == 0) {
        float sum = red[0][0] + red[0][1] + red[0][2] + red[0][3];
        float sq  = red[1][0] + red[1][1] + red[1][2] + red[1][3];
        float mean = sum / cnt;
        float var  = sq / cnt - mean * mean;
        float sc = g[i] * rsqrtf(var + 1e-5f);
        ss[i] = sc;
        ss[16 + i] = bb[i] - mean * sc;
    }
}

// -------------------------------- conv2 via MFMA (BN1+relu fused, att2, stats)
#define H1T_STR 24     // shorts per row
#define H1T_ROWS 448
__global__ __launch_bounds__(256) void k_conv2(const unsigned short* __restrict__ C1b,
        const float* __restrict__ w2kT, const float* __restrict__ a2w1,
        const float* __restrict__ a2b1, const float* __restrict__ a2w2,
        const float* __restrict__ a2b2, const float* __restrict__ ss,
        unsigned short* __restrict__ H2Tb, float* __restrict__ part2) {
    __shared__ __attribute__((aligned(16))) unsigned short H1T[H1T_ROWS * H1T_STR];
    __shared__ __attribute__((aligned(16))) unsigned short Bl[16 * 160];
    __shared__ float p2p[4][16];
    __shared__ float sred[4][2][16];
    int b = blockIdx.x, tid = threadIdx.x;
    int wv = tid >> 6, lane = tid & 63;

    // ---- stage C1 [w][16ic] -> BN1+relu -> bf16 -> H1T rows (vectorized)
    for (int w = tid; w < W1; w += 256) {
        const u32x4* src = (const u32x4*)(C1b + ((size_t)b * W1 + w) * 16);
        u32x4 v0 = src[0], v1 = src[1];
        unsigned int op[8];
        #pragma unroll
        for (int i = 0; i < 8; ++i) {
            unsigned int u = (i < 4) ? v0[i] : v1[i - 4];
            float a = fmaxf(fmaf(bf2f(u),       ss[2*i],     ss[16 + 2*i]),     0.f);
            float c = fmaxf(fmaf(bf2f(u >> 16), ss[2*i + 1], ss[16 + 2*i + 1]), 0.f);
            op[i] = bfbits(a) | (bfbits(c) << 16);
        }
        *(u32x4*)&H1T[w * H1T_STR]     = (u32x4){op[0], op[1], op[2], op[3]};
        *(u32x4*)&H1T[w * H1T_STR + 8] = (u32x4){op[4], op[5], op[6], op[7]};
    }
    if (tid < 128) {   // zero pad rows 432..447
        int r = 432 + (tid >> 3), c = (tid & 7) * 2;
        *(unsigned int*)&H1T[r * H1T_STR + c] = 0u;
    }
    __syncthreads();

    // ---- per-channel means (conflict-free seg sums)
    {
        int chn = tid & 15, seg = tid >> 4;    // 16 segs x 27 w
        float s = 0.f;
        for (int j = 0; j < 27; ++j)
            s += bf2f((unsigned int)H1T[(seg * 27 + j) * H1T_STR + chn]);
        s += __shfl_xor(s, 16);
        s += __shfl_xor(s, 32);
        if ((lane & 48) == 0) p2p[wv][chn] = s;
    }
    __syncthreads();

    // ---- att2 (redundant per-thread, cheap)
    float hv[4];
    #pragma unroll
    for (int j = 0; j < 4; ++j) {
        float a = a2b1[j];
        #pragma unroll
        for (int i = 0; i < 16; ++i) {
            float p2 = (p2p[0][i] + p2p[1][i] + p2p[2][i] + p2p[3][i]) * (1.f / (float)W1);
            a = fmaf(a2w1[j * 16 + i], p2, a);
        }
        hv[j] = fmaxf(a, 0.f);
    }
    float l[4], mx = -1e30f;
    #pragma unroll
    for (int k = 0; k < 4; ++k) {
        float a = a2b2[k];
        #pragma unroll
        for (int j = 0; j < 4; ++j) a = fmaf(a2w2[k * 4 + j], hv[j], a);
        l[k] = a * (1.f / 30.f); mx = fmaxf(mx, l[k]);
    }
    float es = 0.f;
    #pragma unroll
    for (int k = 0; k < 4; ++k) { l[k] = expf(l[k] - mx); es += l[k]; }
    float inv = 1.f / es;
    float at0 = l[0] * inv, at1 = l[1] * inv, at2 = l[2] * inv, at3 = l[3] * inv;
    // ---- mixed kernel from pre-transposed w2kT (coalesced)
    #pragma unroll
    for (int i = 0; i < 10; ++i) {
        int idx = tid + i * 256;
        float v = at0 * w2kT[idx] + at1 * w2kT[2560 + idx]
                + at2 * w2kT[5120 + idx] + at3 * w2kT[7680 + idx];
        Bl[idx] = (unsigned short)bfbits(v);
    }
    __syncthreads();

    // ---- MFMA: 26 m-tiles of 16 w's, K=160 in 5 steps of 32
    int col = lane & 15, kg = lane >> 4;
    bf16x8 bfrag[5];
    #pragma unroll
    for (int s = 0; s < 5; ++s)
        bfrag[s] = *(const bf16x8*)&Bl[col * 160 + s * 32 + kg * 8];
    float s2 = 0.f, q2 = 0.f;
    for (int mt = wv; mt < 26; mt += 4) {
        int wbase = mt * 16;
        f32x4 acc = {0.f, 0.f, 0.f, 0.f};
        #pragma unroll
        for (int s = 0; s < 5; ++s) {
            int tp = 2 * s + (kg >> 1);
            int row = wbase + col + 3 * tp;
            bf16x8 a = *(const bf16x8*)&H1T[row * H1T_STR + (kg & 1) * 8];
            acc = __builtin_amdgcn_mfma_f32_16x16x32_bf16(a, bfrag[s], acc, 0, 0, 0);
        }
        unsigned short* hb = H2Tb + (size_t)b * (16 * W2) + (wbase + kg * 4) * 16 + col;
        #pragma unroll
        for (int r = 0; r < 4; ++r) {
            int w = wbase + kg * 4 + r;
            if (w < W2) {
                float v = acc[r];
                hb[r * 16] = (unsigned short)bfbits(v);
                s2 += v; q2 = fmaf(v, v, q2);
            }
        }
    }
    s2 += __shfl_xor(s2, 16); q2 += __shfl_xor(q2, 16);
    s2 += __shfl_xor(s2, 32); q2 += __shfl_xor(q2, 32);
    if (lane < 16) { sred[wv][0][lane] = s2; sred[wv][1][lane] = q2; }
    __syncthreads();
    if (tid < 16) {
        part2[tid * NSAMP + b] = sred[0][0][tid] + sred[1][0][tid] + sred[2][0][tid] + sred[3][0][tid];
    } else if (tid < 32) {
        int i = tid - 16;
        part2[(16 + i) * NSAMP + b] = sred[0][1][i] + sred[1][1][i] + sred[2][1][i] + sred[3][1][i];
    }
}

// ---------------- BN2+relu+FC: 8 waves/block, wave = sample; fcw in LDS
__global__ __launch_bounds__(512) void k_fc(const unsigned short* __restrict__ H2Tb,
        const float* __restrict__ ss2, const unsigned int* __restrict__ fcwp,
        const float* __restrict__ fcb, float* __restrict__ out) {
    __shared__ u32x2 flo[3443], fhi[3443];   // padded idx p + (p>>4)
    int tid = threadIdx.x, wv = tid >> 6, lane = tid & 63;
    for (int p = tid; p < 3240; p += 512) {
        u32x4 v = ((const u32x4*)fcwp)[p];
        int pi = p + (p >> 4);
        flo[pi] = (u32x2){v[0], v[1]};
        fhi[pi] = (u32x2){v[2], v[3]};
    }
    __syncthreads();
    int b = blockIdx.x * 8 + wv;
    const unsigned int* hb = (const unsigned int*)(H2Tb + (size_t)b * (16 * W2));
    float acc[4] = {};
    for (int p = lane; p < 3240; p += 64) {
        unsigned int u = hb[p];
        int oc = (2 * p) & 15;
        float v0 = fmaxf(fmaf(bf2f(u),       ss2[oc],     ss2[16 + oc]),     0.f);
        float v1 = fmaxf(fmaf(bf2f(u >> 16), ss2[oc + 1], ss2[16 + oc + 1]), 0.f);
        int pi = p + (p >> 4);
        u32x2 lo = flo[pi], hi = fhi[pi];
        acc[0] = fmaf(v0, bf2f(lo[0]),       fmaf(v1, bf2f(hi[0]),       acc[0]));
        acc[1] = fmaf(v0, bf2f(lo[0] >> 16), fmaf(v1, bf2f(hi[0] >> 16), acc[1]));
        acc[2] = fmaf(v0, bf2f(lo[1]),       fmaf(v1, bf2f(hi[1]),       acc[2]));
        acc[3] = fmaf(v0, bf2f(lo[1] >> 16), fmaf(v1, bf2f(hi[1] >> 16), acc[3]));
    }
    #pragma unroll
    for (int m = 1; m < 64; m <<= 1)
        #pragma unroll
        for (int n = 0; n < 4; ++n) acc[n] += __shfl_xor(acc[n], m);
    if (lane < 4) out[b * 4 + lane] = acc[lane] + fcb[lane];
}

extern "C" void kernel_launch(void* const* d_in, const int* in_sizes, int n_in,
                              void* d_out, int out_size, void* d_ws, size_t ws_size,
                              hipStream_t stream) {
    const float* x    = (const float*)d_in[0];
    const float* w1k  = (const float*)d_in[1];
    const float* a1w1 = (const float*)d_in[2];
    const float* a1b1 = (const float*)d_in[3];
    const float* a1w2 = (const float*)d_in[4];
    const float* a1b2 = (const float*)d_in[5];
    const float* g1   = (const float*)d_in[6];
    const float* b1   = (const float*)d_in[7];
    const float* w2k  = (const float*)d_in[8];
    const float* a2w1 = (const float*)d_in[9];
    const float* a2b1 = (const float*)d_in[10];
    const float* a2w2 = (const float*)d_in[11];
    const float* a2b2 = (const float*)d_in[12];
    const float* g2   = (const float*)d_in[13];
    const float* b2   = (const float*)d_in[14];
    const float* fcw  = (const float*)d_in[15];
    const float* fcb  = (const float*)d_in[16];

    float* ws = (float*)d_ws;
    // Region Q: H2Tb bf16 ; part1/part2 @ +14,155,776 ; w2kT/fcwp after
    // Region P @ +26,542,080: C1b bf16 [b][w][16oc]
    unsigned short* H2Tb = (unsigned short*)ws;
    float*          part1 = ws + 14155776;
    float*          part2 = part1 + 32 * NSAMP;
    float*          w2kT  = part2 + 32 * NSAMP;            // 10240 floats
    unsigned int*   fcwp  = (unsigned int*)(w2kT + 10240); // 12960 u32
    unsigned short* C1b  = (unsigned short*)(ws + 26542080);
    unsigned short* basf = (unsigned short*)(ws + 26542080 + 14155776);
    float* ssf   = ws + 26542080 + 14155776 + 114688;

    k_prep<<<165, 256, 0, stream>>>(basf, fcw, fcwp, w2k, w2kT);
    k_fused<<<1024, 256, 0, stream>>>(x, basf, w1k, a1w1, a1b1, a1w2, a1b2, C1b, part1);
    k_statfin2<<<16, 256, 0, stream>>>(part1, g1, b1, ssf, 4096.f * 432.f);
    k_conv2<<<NSAMP, 256, 0, stream>>>(C1b, w2kT, a2w1, a2b1, a2w2, a2b2, ssf, H2Tb, part2);
    k_statfin2<<<16, 256, 0, stream>>>(part2, g2, b2, ssf + 32, 4096.f * 405.f);
    k_fc<<<NSAMP / 8, 512, 0, stream>>>(H2Tb, ssf + 32, fcwp, fcb, (float*)d_out);
}

// Round 12
// 101.926 us; speedup vs baseline: 1.5409x; 1.0395x over previous
//
#include <hip/hip_runtime.h>
#include <math.h>

// Problem constants
#define NB   216        // kept bins
#define W1   432        // transform width = conv1 width
#define W2   405        // conv2 output width
#define NSAMP 4096
#define NFFTC 1747

typedef __bf16 bf16x8 __attribute__((ext_vector_type(8)));
typedef float  f32x4  __attribute__((ext_vector_type(4)));
typedef unsigned int u32x4 __attribute__((ext_vector_type(4)));
typedef unsigned int u32x2 __attribute__((ext_vector_type(2)));

__device__ __forceinline__ unsigned int bfbits(float f) {
    return (unsigned int)__builtin_bit_cast(unsigned short, (__bf16)f);
}
__device__ __forceinline__ float bf2f(unsigned int u) {
    return (float)__builtin_bit_cast(__bf16, (unsigned short)(u & 0xffff));
}

// ---------------- merged prep: basis (tile-major) + fcw pack + w2k transpose
// basf octet g: lane=g&63, kq=(g>>6)&15, nt=g>>10 (0..27)
// col = nt*16 + (lane&15) ; t = kq*32 + (lane>>4)*8 + e
__global__ __launch_bounds__(256) void k_prep(unsigned short* __restrict__ basf,
        const float* __restrict__ fcw, unsigned int* __restrict__ fcwp,
        const float* __restrict__ w2k, float* __restrict__ w2kT) {
    int blk = blockIdx.x, tid = threadIdx.x;
    if (blk < 112) {                       // ---- basis table
        int g = blk * 256 + tid;           // 28,672 octets
        int lane = g & 63;
        int kq = (g >> 6) & 15;
        int nt = g >> 10;
        int w  = nt * 16 + (lane & 15);
        int t0 = kq * 32 + (lane >> 4) * 8;
        unsigned int p[4] = {0u, 0u, 0u, 0u};
        if (w < W1) {
            int k = (w < NB) ? (24 + w) : (w - 192);
            #pragma unroll
            for (int e = 0; e < 8; ++e) {
                int m = (k * (t0 + e)) % NFFTC;
                float ang = (float)m * (float)(6.283185307179586 / 1747.0);
                float c = (w < NB) ? cosf(ang) : -sinf(ang);
                unsigned int bits = bfbits(c * (1.f / 512.f));
                p[e >> 1] |= bits << ((e & 1) * 16);
            }
        }
        u32x4 v = {p[0], p[1], p[2], p[3]};
        *(u32x4*)(basf + (size_t)g * 8) = v;
    } else if (blk < 125) {                // ---- fcw -> packed bf16 pairs
        int p = (blk - 112) * 256 + tid;
        if (p < 3240) {
            int idx0 = 2 * p;
            int w = idx0 >> 4, oc = idx0 & 15;
            unsigned int r[4];
            #pragma unroll
            for (int h = 0; h < 2; ++h) {
                int c = oc + h;
                float n0 = fcw[0 * 6480 + c * W2 + w];
                float n1 = fcw[1 * 6480 + c * W2 + w];
                float n2 = fcw[2 * 6480 + c * W2 + w];
                float n3 = fcw[3 * 6480 + c * W2 + w];
                r[2 * h]     = bfbits(n0) | (bfbits(n1) << 16);
                r[2 * h + 1] = bfbits(n2) | (bfbits(n3) << 16);
            }
            ((u32x4*)fcwp)[p] = (u32x4){r[0], r[1], r[2], r[3]};
        }
    } else {                               // ---- w2k im2col transpose
        int idx = (blk - 125) * 256 + tid;
        if (idx < 10240) {
            int k = idx / 2560, rem = idx - k * 2560;
            int oc = rem / 160, r2 = rem - oc * 160;
            int tp = r2 >> 4, ic = r2 & 15;
            w2kT[idx] = w2k[((k * 16 + oc) * 16 + ic) * 10 + tp];
        }
    }
}

// ------------- FUSED: X->bf16 -> DFT (fb batched from L2) -> conv1(MFMA)
// block = 32 rows (4 samples); wave = col-quarter; 4 blocks/CU, 128 VGPR budget
__global__ __launch_bounds__(256, 4) __attribute__((amdgpu_waves_per_eu(4, 4)))
void k_fused(const float* __restrict__ x,
        const unsigned short* __restrict__ basf,
        const float* __restrict__ w1k, const float* __restrict__ a1w1,
        const float* __restrict__ a1b1, const float* __restrict__ a1w2,
        const float* __restrict__ a1b2,
        unsigned short* __restrict__ C1, float* __restrict__ part1) {
    __shared__ __attribute__((aligned(16))) unsigned short Al[17920]; // 35840 B
    __shared__ float ps[4][4];
    int tid = threadIdx.x, blk = blockIdx.x;
    int wv = tid >> 6, lane = tid & 63;
    int cq = wv;                           // col-quarter
    int kg = lane >> 4, col16 = lane & 15;

    // ---- stage A: X fp32 -> bf16 packed fragments (read once)
    {
        const float* xrow = x + (size_t)(blk * 32 + (tid >> 7) * 16 + (lane & 15)) * 512
                              + ((tid >> 6) & 1) * 32 + (lane >> 4) * 8;
        #pragma unroll
        for (int i = 0; i < 8; ++i) {
            f32x4 a = *(const f32x4*)(xrow + i * 64);
            f32x4 b = *(const f32x4*)(xrow + i * 64 + 4);
            u32x4 v;
            v[0] = bfbits(a[0]) | (bfbits(a[1]) << 16);
            v[1] = bfbits(a[2]) | (bfbits(a[3]) << 16);
            v[2] = bfbits(b[0]) | (bfbits(b[1]) << 16);
            v[3] = bfbits(b[2]) | (bfbits(b[3]) << 16);
            *(u32x4*)&Al[(size_t)(tid + 256 * i) * 8] = v;
        }
    }
    __syncthreads();

    // ---- GEMM: 16 ksteps x 7 col-tiles; 7 fb loads batched, then 14 MFMAs
    f32x4 acc[2][7];
    #pragma unroll
    for (int rh = 0; rh < 2; ++rh)
        #pragma unroll
        for (int j = 0; j < 7; ++j) acc[rh][j] = (f32x4){0.f, 0.f, 0.f, 0.f};
    #pragma unroll
    for (int kq = 0; kq < 16; ++kq) {
        bf16x8 fa0 = *(const bf16x8*)&Al[(((kq >> 1) * 4 + 0 + (kq & 1)) * 64 + lane) * 8];
        bf16x8 fa1 = *(const bf16x8*)&Al[(((kq >> 1) * 4 + 2 + (kq & 1)) * 64 + lane) * 8];
        bf16x8 fb[7];
        #pragma unroll
        for (int j = 0; j < 7; ++j)
            fb[j] = *(const bf16x8*)(basf + (size_t)(((cq * 7 + j) * 16 + kq) * 64 + lane) * 8);
        __builtin_amdgcn_sched_barrier(0);   // keep the 7 loads batched ahead of MFMAs
        #pragma unroll
        for (int j = 0; j < 7; ++j) {
            acc[0][j] = __builtin_amdgcn_mfma_f32_16x16x32_bf16(fa0, fb[j], acc[0][j], 0, 0, 0);
            acc[1][j] = __builtin_amdgcn_mfma_f32_16x16x32_bf16(fa1, fb[j], acc[1][j], 0, 0, 0);
        }
    }

    // ---- per-sample Y partial sums straight from acc
    {
        float s0 = 0.f, s1 = 0.f;
        #pragma unroll
        for (int j = 0; j < 7; ++j)
            #pragma unroll
            for (int e = 0; e < 4; ++e) { s0 += acc[0][j][e]; s1 += acc[1][j][e]; }
        #pragma unroll
        for (int m = 1; m < 32; m <<= 1) { s0 += __shfl_xor(s0, m); s1 += __shfl_xor(s1, m); }
        if ((lane & 31) == 0) {
            int hi = lane >> 5;
            ps[wv][hi] = s0;               // samples 0/1
            ps[wv][2 + hi] = s1;           // samples 2/3
        }
    }
    __syncthreads();   // all fa reads done; Al free for Ys_T

    // ---- write Y transposed: Ys_T[col][row], stride 40 shorts (b64 packed)
    #pragma unroll
    for (int rh = 0; rh < 2; ++rh)
        #pragma unroll
        for (int j = 0; j < 7; ++j) {
            int col = cq * 112 + j * 16 + col16;
            u32x2 pk;
            pk[0] = bfbits(acc[rh][j][0]) | (bfbits(acc[rh][j][1]) << 16);
            pk[1] = bfbits(acc[rh][j][2]) | (bfbits(acc[rh][j][3]) << 16);
            *(u32x2*)&Al[col * 40 + rh * 16 + kg * 4] = pk;
        }
    __syncthreads();

    // ---- fused conv1 via MFMA: wave = sample s; D[oc][16w] per tile
    int s = wv;
    float p1 = (ps[0][s] + ps[1][s] + ps[2][s] + ps[3][s]) * (1.f / (8.f * W1));
    float h = fmaxf(p1 * a1w1[0] + a1b1[0], 0.f);
    float l[4], mx = -1e30f;
    #pragma unroll
    for (int k = 0; k < 4; ++k) { l[k] = (h * a1w2[k] + a1b2[k]) * (1.f / 30.f); mx = fmaxf(mx, l[k]); }
    float es = 0.f;
    #pragma unroll
    for (int k = 0; k < 4; ++k) { l[k] = expf(l[k] - mx); es += l[k]; }
    float inv = 1.f / es;
    float at[4] = {l[0] * inv, l[1] * inv, l[2] * inv, l[3] * inv};

    // A-frag: lane holds kr[oc=col16][ch=kg*8+e]; only kg==0 slice nonzero,
    // so the garbage B values read by kg>=1 lanes are multiplied by ZERO.
    bf16x8 afrag;
    #pragma unroll
    for (int ch = 0; ch < 8; ++ch) {
        float kv = 0.f;
        #pragma unroll
        for (int k = 0; k < 4; ++k) kv = fmaf(at[k], w1k[k * 128 + col16 * 8 + ch], kv);
        afrag[ch] = (kg == 0) ? (__bf16)kv : (__bf16)0.f;
    }
    int b = blk * 4 + s;
    unsigned short* c1o = C1 + (size_t)b * (432 * 16);
    float ssum[4] = {}, ssq[4] = {};
    #pragma unroll 3
    for (int wt = 0; wt < 27; ++wt) {
        // B-frag: Y[ch 0..7][w=wt*16+col16] -- one b128, broadcast across kg
        bf16x8 bfrag = *(const bf16x8*)&Al[(wt * 16 + col16) * 40 + s * 8];
        f32x4 d = {0.f, 0.f, 0.f, 0.f};
        d = __builtin_amdgcn_mfma_f32_16x16x32_bf16(afrag, bfrag, d, 0, 0, 0);
        // D: lane holds D[oc=kg*4+i][w=wt*16+col16]
        u32x2 pk;
        pk[0] = bfbits(d[0]) | (bfbits(d[1]) << 16);
        pk[1] = bfbits(d[2]) | (bfbits(d[3]) << 16);
        *(u32x2*)&c1o[(wt * 16 + col16) * 16 + kg * 4] = pk;
        #pragma unroll
        for (int i = 0; i < 4; ++i) { ssum[i] += d[i]; ssq[i] = fmaf(d[i], d[i], ssq[i]); }
    }
    #pragma unroll
    for (int m = 1; m < 16; m <<= 1)
        #pragma unroll
        for (int c = 0; c < 4; ++c) { ssum[c] += __shfl_xor(ssum[c], m); ssq[c] += __shfl_xor(ssq[c], m); }
    if (col16 == 0) {
        #pragma unroll
        for (int c = 0; c < 4; ++c) {
            part1[(kg * 4 + c) * NSAMP + b] = ssum[c];
            part1[(16 + kg * 4 + c) * NSAMP + b] = ssq[c];
        }
    }
}

// ---------------- stats reduce + finalize: block i handles channel i
__global__ __launch_bounds__(256) void k_statfin2(const float* __restrict__ part,
        const float* __restrict__ g, const float* __restrict__ bb,
        float* __restrict__ ss, float cnt) {
    __shared__ float red[2][4];
    int i = blockIdx.x, tid = threadIdx.x;
    const f32x4* psr = (const f32x4*)(part + (size_t)i * NSAMP);
    const f32x4* qs = (const f32x4*)(part + (size_t)(16 + i) * NSAMP);
    float s = 0.f, q = 0.f;
    #pragma unroll
    for (int jj = 0; jj < 4; ++jj) {
        int j = tid + jj * 256;
        f32x4 a = psr[j], c = qs[j];
        s += a[0] + a[1] + a[2] + a[3];
        q += c[0] + c[1] + c[2] + c[3];
    }
    #pragma unroll
    for (int m = 32; m; m >>= 1) { s += __shfl_xor(s, m); q += __shfl_xor(q, m); }
    if ((tid & 63) == 0) { red[0][tid >> 6] = s; red[1][tid >> 6] = q; }
    __syncthreads();
    if (tid == 0) {
        float sum = red[0][0] + red[0][1] + red[0][2] + red[0][3];
        float sq  = red[1][0] + red[1][1] + red[1][2] + red[1][3];
        float mean = sum / cnt;
        float var  = sq / cnt - mean * mean;
        float sc = g[i] * rsqrtf(var + 1e-5f);
        ss[i] = sc;
        ss[16 + i] = bb[i] - mean * sc;
    }
}

// -------------------------------- conv2 via MFMA (BN1+relu fused, att2, stats)
#define H1T_STR 24     // shorts per row
#define H1T_ROWS 448
__global__ __launch_bounds__(256) void k_conv2(const unsigned short* __restrict__ C1b,
        const float* __restrict__ w2kT, const float* __restrict__ a2w1,
        const float* __restrict__ a2b1, const float* __restrict__ a2w2,
        const float* __restrict__ a2b2, const float* __restrict__ ss,
        unsigned short* __restrict__ H2Tb, float* __restrict__ part2) {
    __shared__ __attribute__((aligned(16))) unsigned short H1T[H1T_ROWS * H1T_STR];
    __shared__ __attribute__((aligned(16))) unsigned short Bl[16 * 160];
    __shared__ float p2p[4][16];
    __shared__ float sred[4][2][16];
    int b = blockIdx.x, tid = threadIdx.x;
    int wv = tid >> 6, lane = tid & 63;

    // ---- stage C1 [w][16ic] -> BN1+relu -> bf16 -> H1T rows (vectorized)
    for (int w = tid; w < W1; w += 256) {
        const u32x4* src = (const u32x4*)(C1b + ((size_t)b * W1 + w) * 16);
        u32x4 v0 = src[0], v1 = src[1];
        unsigned int op[8];
        #pragma unroll
        for (int i = 0; i < 8; ++i) {
            unsigned int u = (i < 4) ? v0[i] : v1[i - 4];
            float a = fmaxf(fmaf(bf2f(u),       ss[2*i],     ss[16 + 2*i]),     0.f);
            float c = fmaxf(fmaf(bf2f(u >> 16), ss[2*i + 1], ss[16 + 2*i + 1]), 0.f);
            op[i] = bfbits(a) | (bfbits(c) << 16);
        }
        *(u32x4*)&H1T[w * H1T_STR]     = (u32x4){op[0], op[1], op[2], op[3]};
        *(u32x4*)&H1T[w * H1T_STR + 8] = (u32x4){op[4], op[5], op[6], op[7]};
    }
    if (tid < 128) {   // zero pad rows 432..447
        int r = 432 + (tid >> 3), c = (tid & 7) * 2;
        *(unsigned int*)&H1T[r * H1T_STR + c] = 0u;
    }
    __syncthreads();

    // ---- per-channel means (conflict-free seg sums)
    {
        int chn = tid & 15, seg = tid >> 4;    // 16 segs x 27 w
        float s = 0.f;
        for (int j = 0; j < 27; ++j)
            s += bf2f((unsigned int)H1T[(seg * 27 + j) * H1T_STR + chn]);
        s += __shfl_xor(s, 16);
        s += __shfl_xor(s, 32);
        if ((lane & 48) == 0) p2p[wv][chn] = s;
    }
    __syncthreads();

    // ---- att2 (redundant per-thread, cheap)
    float hv[4];
    #pragma unroll
    for (int j = 0; j < 4; ++j) {
        float a = a2b1[j];
        #pragma unroll
        for (int i = 0; i < 16; ++i) {
            float p2 = (p2p[0][i] + p2p[1][i] + p2p[2][i] + p2p[3][i]) * (1.f / (float)W1);
            a = fmaf(a2w1[j * 16 + i], p2, a);
        }
        hv[j] = fmaxf(a, 0.f);
    }
    float l[4], mx = -1e30f;
    #pragma unroll
    for (int k = 0; k < 4; ++k) {
        float a = a2b2[k];
        #pragma unroll
        for (int j = 0; j < 4; ++j) a = fmaf(a2w2[k * 4 + j], hv[j], a);
        l[k] = a * (1.f / 30.f); mx = fmaxf(mx, l[k]);
    }
    float es = 0.f;
    #pragma unroll
    for (int k = 0; k < 4; ++k) { l[k] = expf(l[k] - mx); es += l[k]; }
    float inv = 1.f / es;
    float at0 = l[0] * inv, at1 = l[1] * inv, at2 = l[2] * inv, at3 = l[3] * inv;
    // ---- mixed kernel from pre-transposed w2kT (coalesced)
    #pragma unroll
    for (int i = 0; i < 10; ++i) {
        int idx = tid + i * 256;
        float v = at0 * w2kT[idx] + at1 * w2kT[2560 + idx]
                + at2 * w2kT[5120 + idx] + at3 * w2kT[7680 + idx];
        Bl[idx] = (unsigned short)bfbits(v);
    }
    __syncthreads();

    // ---- MFMA: 26 m-tiles of 16 w's, K=160 in 5 steps of 32
    int col = lane & 15, kg = lane >> 4;
    bf16x8 bfrag[5];
    #pragma unroll
    for (int s = 0; s < 5; ++s)
        bfrag[s] = *(const bf16x8*)&Bl[col * 160 + s * 32 + kg * 8];
    float s2 = 0.f, q2 = 0.f;
    for (int mt = wv; mt < 26; mt += 4) {
        int wbase = mt * 16;
        f32x4 acc = {0.f, 0.f, 0.f, 0.f};
        #pragma unroll
        for (int s = 0; s < 5; ++s) {
            int tp = 2 * s + (kg >> 1);
            int row = wbase + col + 3 * tp;
            bf16x8 a = *(const bf16x8*)&H1T[row * H1T_STR + (kg & 1) * 8];
            acc = __builtin_amdgcn_mfma_f32_16x16x32_bf16(a, bfrag[s], acc, 0, 0, 0);
        }
        unsigned short* hb = H2Tb + (size_t)b * (16 * W2) + (wbase + kg * 4) * 16 + col;
        #pragma unroll
        for (int r = 0; r < 4; ++r) {
            int w = wbase + kg * 4 + r;
            if (w < W2) {
                float v = acc[r];
                hb[r * 16] = (unsigned short)bfbits(v);
                s2 += v; q2 = fmaf(v, v, q2);
            }
        }
    }
    s2 += __shfl_xor(s2, 16); q2 += __shfl_xor(q2, 16);
    s2 += __shfl_xor(s2, 32); q2 += __shfl_xor(q2, 32);
    if (lane < 16) { sred[wv][0][lane] = s2; sred[wv][1][lane] = q2; }
    __syncthreads();
    if (tid < 16) {
        part2[tid * NSAMP + b] = sred[0][0][tid] + sred[1][0][tid] + sred[2][0][tid] + sred[3][0][tid];
    } else if (tid < 32) {
        int i = tid - 16;
        part2[(16 + i) * NSAMP + b] = sred[0][1][i] + sred[1][1][i] + sred[2][1][i] + sred[3][1][i];
    }
}

// ---------------- BN2+relu+FC: 8 waves/block, wave = sample; fcw in LDS
__global__ __launch_bounds__(512) void k_fc(const unsigned short* __restrict__ H2Tb,
        const float* __restrict__ ss2, const unsigned int* __restrict__ fcwp,
        const float* __restrict__ fcb, float* __restrict__ out) {
    __shared__ u32x2 flo[3443], fhi[3443];   // padded idx p + (p>>4)
    int tid = threadIdx.x, wv = tid >> 6, lane = tid & 63;
    for (int p = tid; p < 3240; p += 512) {
        u32x4 v = ((const u32x4*)fcwp)[p];
        int pi = p + (p >> 4);
        flo[pi] = (u32x2){v[0], v[1]};
        fhi[pi] = (u32x2){v[2], v[3]};
    }
    __syncthreads();
    int b = blockIdx.x * 8 + wv;
    const unsigned int* hb = (const unsigned int*)(H2Tb + (size_t)b * (16 * W2));
    float acc[4] = {};
    for (int p = lane; p < 3240; p += 64) {
        unsigned int u = hb[p];
        int oc = (2 * p) & 15;
        float v0 = fmaxf(fmaf(bf2f(u),       ss2[oc],     ss2[16 + oc]),     0.f);
        float v1 = fmaxf(fmaf(bf2f(u >> 16), ss2[oc + 1], ss2[16 + oc + 1]), 0.f);
        int pi = p + (p >> 4);
        u32x2 lo = flo[pi], hi = fhi[pi];
        acc[0] = fmaf(v0, bf2f(lo[0]),       fmaf(v1, bf2f(hi[0]),       acc[0]));
        acc[1] = fmaf(v0, bf2f(lo[0] >> 16), fmaf(v1, bf2f(hi[0] >> 16), acc[1]));
        acc[2] = fmaf(v0, bf2f(lo[1]),       fmaf(v1, bf2f(hi[1]),       acc[2]));
        acc[3] = fmaf(v0, bf2f(lo[1] >> 16), fmaf(v1, bf2f(hi[1] >> 16), acc[3]));
    }
    #pragma unroll
    for (int m = 1; m < 64; m <<= 1)
        #pragma unroll
        for (int n = 0; n < 4; ++n) acc[n] += __shfl_xor(acc[n], m);
    if (lane < 4) out[b * 4 + lane] = acc[lane] + fcb[lane];
}

extern "C" void kernel_launch(void* const* d_in, const int* in_sizes, int n_in,
                              void* d_out, int out_size, void* d_ws, size_t ws_size,
                              hipStream_t stream) {
    const float* x    = (const float*)d_in[0];
    const float* w1k  = (const float*)d_in[1];
    const float* a1w1 = (const float*)d_in[2];
    const float* a1b1 = (const float*)d_in[3];
    const float* a1w2 = (const float*)d_in[4];
    const float* a1b2 = (const float*)d_in[5];
    const float* g1   = (const float*)d_in[6];
    const float* b1   = (const float*)d_in[7];
    const float* w2k  = (const float*)d_in[8];
    const float* a2w1 = (const float*)d_in[9];
    const float* a2b1 = (const float*)d_in[10];
    const float* a2w2 = (const float*)d_in[11];
    const float* a2b2 = (const float*)d_in[12];
    const float* g2   = (const float*)d_in[13];
    const float* b2   = (const float*)d_in[14];
    const float* fcw  = (const float*)d_in[15];
    const float* fcb  = (const float*)d_in[16];

    float* ws = (float*)d_ws;
    // Region Q: H2Tb bf16 ; part1/part2 @ +14,155,776 ; w2kT/fcwp after
    // Region P @ +26,542,080: C1b bf16 [b][w][16oc]
    unsigned short* H2Tb = (unsigned short*)ws;
    float*          part1 = ws + 14155776;
    float*          part2 = part1 + 32 * NSAMP;
    float*          w2kT  = part2 + 32 * NSAMP;            // 10240 floats
    unsigned int*   fcwp  = (unsigned int*)(w2kT + 10240); // 12960 u32
    unsigned short* C1b  = (unsigned short*)(ws + 26542080);
    unsigned short* basf = (unsigned short*)(ws + 26542080 + 14155776);
    float* ssf   = ws + 26542080 + 14155776 + 114688;

    k_prep<<<165, 256, 0, stream>>>(basf, fcw, fcwp, w2k, w2kT);
    k_fused<<<1024, 256, 0, stream>>>(x, basf, w1k, a1w1, a1b1, a1w2, a1b2, C1b, part1);
    k_statfin2<<<16, 256, 0, stream>>>(part1, g1, b1, ssf, 4096.f * 432.f);
    k_conv2<<<NSAMP, 256, 0, stream>>>(C1b, w2kT, a2w1, a2b1, a2w2, a2b2, ssf, H2Tb, part2);
    k_statfin2<<<16, 256, 0, stream>>>(part2, g2, b2, ssf + 32, 4096.f * 405.f);
    k_fc<<<NSAMP / 8, 512, 0, stream>>>(H2Tb, ssf + 32, fcwp, fcb, (float*)d_out);
}